// Round 6
// baseline (602.588 us; speedup 1.0000x reference)
//
#include <hip/hip_runtime.h>
#include <math.h>

// GCN 5-layer: per layer relu(A @ (h @ W) + b), A = sym-normalized adj w/ self-loops.
// CSR-by-dst build, aggregate on the narrow side of each GEMM, fold dinv[src]
// row-scaling into GEMM epilogues. All fp32.
// R4: radix build (~50us). R5: float4 agg (VALU 31->21%, dur flat -> not issue-bound).
// R6: column-sliced XCD-pinned aggregation: 8-col slices (3.2MB) pinned to XCDs via
//     blockIdx%SLICES so the gather working set is L2-resident; csr re-streamed per
//     slice with nontemporal loads; GEMM epilogues write sliced layout directly.

#define NBIN_MAX 256
#define BSHIFT 9
#define BINW 512
#define CHUNK 8192

// ---------------- graph build (R4 radix pipeline) ----------------
__global__ __launch_bounds__(256) void k_hist(const int* __restrict__ dst, int E,
                                              int nbin, int* __restrict__ binCnt) {
    __shared__ int h[NBIN_MAX];
    int t = threadIdx.x;
    for (int i = t; i < nbin; i += 256) h[i] = 0;
    __syncthreads();
    for (int e = blockIdx.x * 256 + t; e < E; e += gridDim.x * 256)
        atomicAdd(&h[dst[e] >> BSHIFT], 1);
    __syncthreads();
    for (int i = t; i < nbin; i += 256)
        if (h[i]) atomicAdd(&binCnt[i], h[i]);
}

__global__ __launch_bounds__(256) void k_binscan(const int* __restrict__ binCnt,
                                                 int nbin, int* __restrict__ binBase,
                                                 int* __restrict__ binCur) {
    __shared__ int sh[256];
    int t = threadIdx.x;
    int v = (t < nbin) ? binCnt[t] : 0;
    sh[t] = v;
    __syncthreads();
    for (int d = 1; d < 256; d <<= 1) {
        int u = (t >= d) ? sh[t - d] : 0;
        __syncthreads();
        sh[t] += u;
        __syncthreads();
    }
    int ex = sh[t] - v;
    if (t < nbin) { binBase[t] = ex; binCur[t] = ex; }
    if (t == nbin - 1) binBase[nbin] = sh[t];
}

__global__ __launch_bounds__(256) void k_binfill(const int* __restrict__ src,
                                                 const int* __restrict__ dst, int E,
                                                 int nbin, int* __restrict__ binCur,
                                                 unsigned* __restrict__ tmp) {
    __shared__ int h[NBIN_MAX];
    __shared__ int res[NBIN_MAX];
    int t = threadIdx.x;
    int e0 = blockIdx.x * CHUNK;
    int e1 = min(e0 + CHUNK, E);
    for (int i = t; i < nbin; i += 256) h[i] = 0;
    __syncthreads();
    for (int e = e0 + t; e < e1; e += 256)
        atomicAdd(&h[dst[e] >> BSHIFT], 1);
    __syncthreads();
    for (int i = t; i < nbin; i += 256)
        res[i] = h[i] ? atomicAdd(&binCur[i], h[i]) : 0;
    __syncthreads();
    for (int i = t; i < nbin; i += 256) h[i] = 0;
    __syncthreads();
    for (int e = e0 + t; e < e1; e += 256) {
        int d = dst[e];
        int b = d >> BSHIFT;
        int p = res[b] + atomicAdd(&h[b], 1);
        tmp[p] = ((unsigned)src[e] << BSHIFT) | (unsigned)(d & (BINW - 1));
    }
}

__global__ __launch_bounds__(256) void k_csr(const unsigned* __restrict__ tmp,
                                             const int* __restrict__ binBase,
                                             int n, int nbin,
                                             float* __restrict__ dinv,
                                             int* __restrict__ offs,
                                             int* __restrict__ csr) {
    __shared__ int ldeg[BINW];
    __shared__ int loff[BINW];
    __shared__ int pair[256];
    int b = blockIdx.x;
    int t = threadIdx.x;
    ldeg[t] = 0; ldeg[t + 256] = 0;
    __syncthreads();
    int lo = binBase[b], hi = binBase[b + 1];
    for (int p = lo + t; p < hi; p += 256)
        atomicAdd(&ldeg[tmp[p] & (BINW - 1u)], 1);
    __syncthreads();
    int a0 = ldeg[2 * t], a1 = ldeg[2 * t + 1];
    pair[t] = a0 + a1;
    __syncthreads();
    int v = pair[t];
    for (int d = 1; d < 256; d <<= 1) {
        int u = (t >= d) ? pair[t - d] : 0;
        __syncthreads();
        pair[t] += u;
        __syncthreads();
    }
    int ex = pair[t] - v;
    loff[2 * t] = ex;
    loff[2 * t + 1] = ex + a0;
    __syncthreads();
    int v0 = b << BSHIFT;
    for (int i = t; i < BINW; i += 256) {
        int vv = v0 + i;
        if (vv < n) {
            offs[vv] = lo + loff[i];
            dinv[vv] = 1.0f / sqrtf((float)(ldeg[i] + 1));
        }
    }
    if (t == 0 && b == nbin - 1) offs[n] = hi;
    __syncthreads();
    ldeg[t] = 0; ldeg[t + 256] = 0;
    __syncthreads();
    for (int p = lo + t; p < hi; p += 256) {
        unsigned u = tmp[p];
        int d0 = (int)(u & (BINW - 1u));
        int pos = loff[d0] + atomicAdd(&ldeg[d0], 1);
        csr[lo + pos] = (int)(u >> BSHIFT);
    }
}

// ---------------- R6: slice prepass for x (scale by dinv, 8-col slices) ----------------
__global__ __launch_bounds__(256) void k_slice(const float* __restrict__ x,
                                               const float* __restrict__ dinv,
                                               float* __restrict__ xs, int n) {
    int i = blockIdx.x * 256 + threadIdx.x;   // over n*16 col-groups of 4
    int v = i >> 4;
    if (v >= n) return;
    int c4 = i & 15;
    float4 a = *(const float4*)&x[(size_t)v * 64 + c4 * 4];
    float dv = dinv[v];
    a.x *= dv; a.y *= dv; a.z *= dv; a.w *= dv;
    int slice = c4 >> 1, j = c4 & 1;
    *(float4*)&xs[(size_t)slice * n * 8 + (size_t)v * 8 + j * 4] = a;
}

// ---------------- R6: sliced XCD-pinned aggregation ----------------
// S sliced: SLICES slices of 8 cols (slice stride n*8). Y row-major (stride W).
// Per wave: 4 row-groups of 16 lanes; per group: 2 lanes x float4 cover the
// 8-col slice, 8 edge slots, x2 unroll. out = act(dinv[v]*(sum+self) + bias).
template <int W, int SLICES, bool RELU, bool BIAS>
__global__ __launch_bounds__(256) void k_aggs(const float* __restrict__ S,
                                              const float* __restrict__ dinv,
                                              const int* __restrict__ offs,
                                              const int* __restrict__ csr,
                                              const float* __restrict__ bg,
                                              float* __restrict__ Y, int n) {
    int lane = threadIdx.x & 63;
    int wave = threadIdx.x >> 6;
    int slice = blockIdx.x % SLICES;          // XCD pin (blockIdx round-robin)
    int vb = (blockIdx.x / SLICES) * 16 + wave * 4;
    int rg = lane >> 4;
    int l16 = lane & 15;
    int g = l16 >> 1;
    int j = l16 & 1;
    int v = vb + rg;
    bool act = v < n;
    const float* Sb = S + (size_t)slice * n * 8;
    float dv = act ? dinv[v] : 0.f;
    float4 acc0 = make_float4(0.f, 0.f, 0.f, 0.f);
    float4 acc1 = make_float4(0.f, 0.f, 0.f, 0.f);
    int e0 = 0, re = 0;
    if (act) { e0 = offs[v]; re = offs[v + 1]; }
    if (act && g == 0)                        // self-loop (S pre-scaled by dinv[row])
        acc0 = *(const float4*)&Sb[(size_t)v * 8 + j * 4];
    for (int eb = e0; eb < re; eb += 16) {
        int ea = eb + g, ec = eb + 8 + g;
        if (ea < re) {
            int u = __builtin_nontemporal_load(&csr[ea]);
            float4 a = *(const float4*)&Sb[(size_t)u * 8 + j * 4];
            acc0.x += a.x; acc0.y += a.y; acc0.z += a.z; acc0.w += a.w;
        }
        if (ec < re) {
            int u = __builtin_nontemporal_load(&csr[ec]);
            float4 a = *(const float4*)&Sb[(size_t)u * 8 + j * 4];
            acc1.x += a.x; acc1.y += a.y; acc1.z += a.z; acc1.w += a.w;
        }
    }
    acc0.x += acc1.x; acc0.y += acc1.y; acc0.z += acc1.z; acc0.w += acc1.w;
#pragma unroll
    for (int d = 2; d < 16; d <<= 1) {        // reduce 8 edge groups (same j, same rg)
        acc0.x += __shfl_xor(acc0.x, d);
        acc0.y += __shfl_xor(acc0.y, d);
        acc0.z += __shfl_xor(acc0.z, d);
        acc0.w += __shfl_xor(acc0.w, d);
    }
    if (act && l16 < 2) {
        float4 r;
        r.x = dv * acc0.x; r.y = dv * acc0.y; r.z = dv * acc0.z; r.w = dv * acc0.w;
        if (BIAS) {
            float4 bv = *(const float4*)&bg[slice * 8 + j * 4];
            r.x += bv.x; r.y += bv.y; r.z += bv.z; r.w += bv.w;
        }
        if (RELU) {
            r.x = fmaxf(r.x, 0.f); r.y = fmaxf(r.y, 0.f);
            r.z = fmaxf(r.z, 0.f); r.w = fmaxf(r.w, 0.f);
        }
        *(float4*)&Y[(size_t)v * W + slice * 8 + j * 4] = r;
    }
}

// W=16 aggregation with gemm5 fused (S row-major): h4 = relu(dinv*sum + b4);
// Y[v] = (h4 . W5) * dinv[v]
__global__ __launch_bounds__(256) void k_agg16_gemm5(const float* __restrict__ S,
                                                     const float* __restrict__ dinv,
                                                     const int* __restrict__ offs,
                                                     const int* __restrict__ csr,
                                                     const float* __restrict__ b4,
                                                     const float* __restrict__ W5,
                                                     float* __restrict__ Y, int n) {
    constexpr int W = 16, LPR = 4, G = 16;
    int lane = threadIdx.x & 63;
    int wave = threadIdx.x >> 6;
    int v = blockIdx.x * 4 + wave;
    if (v >= n) return;
    int g = lane / LPR;
    int j = lane % LPR;
    float dv = dinv[v];
    float4 acc0 = make_float4(0.f, 0.f, 0.f, 0.f);
    float4 acc1 = make_float4(0.f, 0.f, 0.f, 0.f);
    if (g == 0) acc0 = *(const float4*)&S[(size_t)v * W + j * 4];
    int e0 = offs[v], re = offs[v + 1];
    for (int eb = e0; eb < re; eb += 2 * G) {
        int ea = eb + g, ec = eb + G + g;
        if (ea < re) {
            int u = csr[ea];
            float4 a = *(const float4*)&S[(size_t)u * W + j * 4];
            acc0.x += a.x; acc0.y += a.y; acc0.z += a.z; acc0.w += a.w;
        }
        if (ec < re) {
            int u = csr[ec];
            float4 a = *(const float4*)&S[(size_t)u * W + j * 4];
            acc1.x += a.x; acc1.y += a.y; acc1.z += a.z; acc1.w += a.w;
        }
    }
    acc0.x += acc1.x; acc0.y += acc1.y; acc0.z += acc1.z; acc0.w += acc1.w;
#pragma unroll
    for (int d = LPR; d < 64; d <<= 1) {
        acc0.x += __shfl_xor(acc0.x, d);
        acc0.y += __shfl_xor(acc0.y, d);
        acc0.z += __shfl_xor(acc0.z, d);
        acc0.w += __shfl_xor(acc0.w, d);
    }
    float4 bv = *(const float4*)&b4[j * 4];
    float4 w5 = *(const float4*)&W5[j * 4];
    float hx = fmaxf(dv * acc0.x + bv.x, 0.f);
    float hy = fmaxf(dv * acc0.y + bv.y, 0.f);
    float hz = fmaxf(dv * acc0.z + bv.z, 0.f);
    float hw = fmaxf(dv * acc0.w + bv.w, 0.f);
    float p = hx * w5.x + hy * w5.y + hz * w5.z + hw * w5.w;
    p += __shfl_xor(p, 1);
    p += __shfl_xor(p, 2);
    if (lane == 0) Y[v] = p * dv;
}

__global__ __launch_bounds__(256) void k_agg1(const float* __restrict__ S,
                                              const float* __restrict__ dinv,
                                              const int* __restrict__ offs,
                                              const int* __restrict__ csr,
                                              const float* __restrict__ bg,
                                              float* __restrict__ Y, int n) {
    int v = blockIdx.x * 256 + threadIdx.x;
    if (v >= n) return;
    float sum = S[v];
    int e = offs[v], re = offs[v + 1];
    for (; e < re; ++e) sum += S[csr[e]];
    Y[v] = dinv[v] * sum + bg[0];
}

// ---------------- tall-skinny GEMMs ----------------
// EPI==0: += bias, relu, row-major out. EPI==1: *= dinv[row]; OSL>0 -> write
// OSL slices of 8 cols (slice stride nrows*8), else row-major.
template <int IN, int OUT, int EPI, int OSL>
__global__ __launch_bounds__(256) void k_gemm(const float* __restrict__ X,
                                              const float* __restrict__ Wg,
                                              const float* __restrict__ bg,
                                              const float* __restrict__ dinv,
                                              float* __restrict__ Y, int nrows) {
    constexpr int TPR = OUT / 4;
    constexpr int GROUPS = 256 / TPR;
    constexpr int ROWS = GROUPS * 2;
    __shared__ __align__(16) float Wl[IN * OUT];
    __shared__ __align__(16) float xl[ROWS * IN];
    __shared__ float bl[OUT];
    int tid = threadIdx.x;
    for (int i = tid; i < IN * OUT; i += 256) Wl[i] = Wg[i];
    if (EPI == 0)
        for (int i = tid; i < OUT; i += 256) bl[i] = bg[i];
    int base = blockIdx.x * ROWS;
    for (int i = tid; i < ROWS * IN; i += 256) {
        int r = base + i / IN;
        xl[i] = (r < nrows) ? X[(size_t)base * IN + i] : 0.0f;
    }
    __syncthreads();
    int g = tid / TPR;
    int c0 = (tid % TPR) * 4;
    int r0 = base + g * 2, r1 = r0 + 1;
    int l0 = (g * 2) * IN, l1 = l0 + IN;
    float4 acc0 = make_float4(0.f, 0.f, 0.f, 0.f);
    float4 acc1 = make_float4(0.f, 0.f, 0.f, 0.f);
#pragma unroll 8
    for (int k = 0; k < IN; ++k) {
        float4 w = *(const float4*)&Wl[k * OUT + c0];
        float a0 = xl[l0 + k], a1 = xl[l1 + k];
        acc0.x += a0 * w.x; acc0.y += a0 * w.y; acc0.z += a0 * w.z; acc0.w += a0 * w.w;
        acc1.x += a1 * w.x; acc1.y += a1 * w.y; acc1.z += a1 * w.z; acc1.w += a1 * w.w;
    }
    if (EPI == 0) {
        float bx = bl[c0], by = bl[c0 + 1], bz = bl[c0 + 2], bw = bl[c0 + 3];
        acc0.x = fmaxf(acc0.x + bx, 0.f); acc0.y = fmaxf(acc0.y + by, 0.f);
        acc0.z = fmaxf(acc0.z + bz, 0.f); acc0.w = fmaxf(acc0.w + bw, 0.f);
        acc1.x = fmaxf(acc1.x + bx, 0.f); acc1.y = fmaxf(acc1.y + by, 0.f);
        acc1.z = fmaxf(acc1.z + bz, 0.f); acc1.w = fmaxf(acc1.w + bw, 0.f);
        if (r0 < nrows) *(float4*)&Y[(size_t)r0 * OUT + c0] = acc0;
        if (r1 < nrows) *(float4*)&Y[(size_t)r1 * OUT + c0] = acc1;
    } else {
        if (r0 < nrows) { float d0 = dinv[r0]; acc0.x *= d0; acc0.y *= d0; acc0.z *= d0; acc0.w *= d0; }
        if (r1 < nrows) { float d1 = dinv[r1]; acc1.x *= d1; acc1.y *= d1; acc1.z *= d1; acc1.w *= d1; }
        if (OSL > 0) {
            size_t sa = (size_t)(c0 >> 3) * nrows * 8 + (size_t)r0 * 8 + (c0 & 7);
            if (r0 < nrows) *(float4*)&Y[sa] = acc0;
            if (r1 < nrows) *(float4*)&Y[sa + 8] = acc1;
        } else {
            if (r0 < nrows) *(float4*)&Y[(size_t)r0 * OUT + c0] = acc0;
            if (r1 < nrows) *(float4*)&Y[(size_t)r1 * OUT + c0] = acc1;
        }
    }
}

extern "C" void kernel_launch(void* const* d_in, const int* in_sizes, int n_in,
                              void* d_out, int out_size, void* d_ws, size_t ws_size,
                              hipStream_t stream) {
    const float* x  = (const float*)d_in[0];
    const int*   ei = (const int*)d_in[1];
    const float* W1 = (const float*)d_in[2];  const float* b1 = (const float*)d_in[3];
    const float* W2 = (const float*)d_in[4];  const float* b2 = (const float*)d_in[5];
    const float* W3 = (const float*)d_in[6];  const float* b3 = (const float*)d_in[7];
    const float* W4 = (const float*)d_in[8];  const float* b4 = (const float*)d_in[9];
    const float* W5 = (const float*)d_in[10]; const float* b5 = (const float*)d_in[11];

    const int N = in_sizes[0] / 64;   // 100000
    const int E = in_sizes[1] / 2;    // 1600000
    const int* src = ei;
    const int* dst = ei + E;
    const int nbin = (N + BINW - 1) / BINW;   // 196

    char* ws = (char*)d_ws;
    size_t off = 0;
    auto alloc = [&](size_t bytes) -> void* {
        void* p = ws + off;
        off = (off + bytes + 255) & ~(size_t)255;
        return p;
    };
    float* dinv    = (float*)alloc((size_t)N * 4);
    int*   offs    = (int*)alloc((size_t)(N + 1) * 4);
    int*   binCnt  = (int*)alloc((size_t)NBIN_MAX * 4);
    int*   binBase = (int*)alloc((size_t)(NBIN_MAX + 1) * 4);
    int*   binCur  = (int*)alloc((size_t)NBIN_MAX * 4);
    int*   csr     = (int*)alloc((size_t)E * 4);
    float* s5      = (float*)alloc((size_t)N * 4);
    float* A       = (float*)alloc((size_t)N * 128 * 4);  // xs -> h1 -> h3
    float* B       = (float*)alloc((size_t)N * 64 * 4);   // agg1/S2/S3/S4
    float* C       = (float*)alloc((size_t)N * 64 * 4);   // tmp -> h2
    unsigned* tmp  = (unsigned*)C;
    float* xs      = A;                                    // sliced x (dead before GEMM1 writes A)

    hipMemsetAsync(binCnt, 0, (size_t)NBIN_MAX * 4, stream);

    k_hist<<<256, 256, 0, stream>>>(dst, E, nbin, binCnt);
    k_binscan<<<1, 256, 0, stream>>>(binCnt, nbin, binBase, binCur);
    k_binfill<<<(E + CHUNK - 1) / CHUNK, 256, 0, stream>>>(src, dst, E, nbin, binCur, tmp);
    k_csr<<<nbin, 256, 0, stream>>>(tmp, binBase, N, nbin, dinv, offs, csr);

    const int grow = (N + 15) / 16;
    // Layer 1: slice+scale x, sliced agg (64 wide), then h1 = relu(agg1 @ W1 + b1)
    k_slice<<<(N * 16 + 255) / 256, 256, 0, stream>>>(x, dinv, xs, N);
    k_aggs<64, 8, false, false><<<grow * 8, 256, 0, stream>>>(xs, dinv, offs, csr, nullptr, B, N);
    k_gemm<64, 128, 0, 0><<<(N + 15) / 16, 256, 0, stream>>>(B, W1, b1, nullptr, A, N);
    // Layer 2: S2 = (h1 @ W2)*dinv written sliced(8), h2 = relu(A.S2 + b2)
    k_gemm<128, 64, 1, 8><<<(N + 31) / 32, 256, 0, stream>>>(A, W2, nullptr, dinv, B, N);
    k_aggs<64, 8, true, true><<<grow * 8, 256, 0, stream>>>(B, dinv, offs, csr, b2, C, N);
    // Layer 3: S3 sliced(4), h3 = relu(A.S3 + b3)
    k_gemm<64, 32, 1, 4><<<(N + 63) / 64, 256, 0, stream>>>(C, W3, nullptr, dinv, B, N);
    k_aggs<32, 4, true, true><<<grow * 4, 256, 0, stream>>>(B, dinv, offs, csr, b3, A, N);
    // Layer 4: S4 row-major, fused agg+gemm5 -> s5 (h4 never stored)
    k_gemm<32, 16, 1, 0><<<(N + 127) / 128, 256, 0, stream>>>(A, W4, nullptr, dinv, B, N);
    k_agg16_gemm5<<<(N + 3) / 4, 256, 0, stream>>>(B, dinv, offs, csr, b4, W5, s5, N);
    // Layer 5: out = A.s5 + b5
    k_agg1<<<(N + 255) / 256, 256, 0, stream>>>(s5, dinv, offs, csr, b5, (float*)d_out, N);
}

// Round 8
// 448.693 us; speedup vs baseline: 1.3430x; 1.3430x over previous
//
#include <hip/hip_runtime.h>
#include <math.h>

// GCN 5-layer: per layer relu(A @ (h @ W) + b), A = sym-normalized adj w/ self-loops.
// CSR-by-dst build, aggregate on the narrow side of each GEMM, fold dinv[src]
// row-scaling into GEMM epilogues. All fp32.
// R4: radix build. R5: float4 agg, 1 wave/row, 256B gathers (optimal line touches E*4).
// R6: sliced agg FAILED (2x line touches -> 2x slower despite 3x less HBM fetch).
// R7: CRASHED — binfill covered 1024/4096 edges per block (missing loop), k_csr
//     read poison tmp -> OOB gather. R8 = R7 with binfill loop fixed (CHUNK=2048,
//     strided int4 x2 + tail, identical pattern in count & write passes).

#define NBIN_MAX 256
#define BSHIFT 9
#define BINW 512
#define CHUNK 2048

// ---------------- graph build (radix pipeline) ----------------
__global__ __launch_bounds__(256) void k_hist(const int* __restrict__ dst, int E,
                                              int nbin, int* __restrict__ binCnt) {
    __shared__ int h[NBIN_MAX];
    int t = threadIdx.x;
    for (int i = t; i < nbin; i += 256) h[i] = 0;
    __syncthreads();
    int e4 = (blockIdx.x * 256 + t) * 4;
    int stride = gridDim.x * 256 * 4;
    for (; e4 + 3 < E; e4 += stride) {
        int4 d = *(const int4*)&dst[e4];
        atomicAdd(&h[d.x >> BSHIFT], 1);
        atomicAdd(&h[d.y >> BSHIFT], 1);
        atomicAdd(&h[d.z >> BSHIFT], 1);
        atomicAdd(&h[d.w >> BSHIFT], 1);
    }
    for (; e4 < E; ++e4) atomicAdd(&h[dst[e4] >> BSHIFT], 1);
    __syncthreads();
    for (int i = t; i < nbin; i += 256)
        if (h[i]) atomicAdd(&binCnt[i], h[i]);
}

__global__ __launch_bounds__(256) void k_binscan(const int* __restrict__ binCnt,
                                                 int nbin, int* __restrict__ binBase,
                                                 int* __restrict__ binCur) {
    __shared__ int sh[256];
    int t = threadIdx.x;
    int v = (t < nbin) ? binCnt[t] : 0;
    sh[t] = v;
    __syncthreads();
    for (int d = 1; d < 256; d <<= 1) {
        int u = (t >= d) ? sh[t - d] : 0;
        __syncthreads();
        sh[t] += u;
        __syncthreads();
    }
    int ex = sh[t] - v;
    if (t < nbin) { binBase[t] = ex; binCur[t] = ex; }
    if (t == nbin - 1) binBase[nbin] = sh[t];
}

__global__ __launch_bounds__(256) void k_binfill(const int* __restrict__ src,
                                                 const int* __restrict__ dst, int E,
                                                 int nbin, int* __restrict__ binCur,
                                                 unsigned* __restrict__ tmp) {
    __shared__ int h[NBIN_MAX];
    __shared__ int res[NBIN_MAX];
    int t = threadIdx.x;
    int e0 = blockIdx.x * CHUNK;
    int e1 = min(e0 + CHUNK, E);
    int vend = e0 + ((e1 - e0) & ~3);      // vectorizable part (multiple of 4)
    for (int i = t; i < nbin; i += 256) h[i] = 0;
    __syncthreads();
    // count pass
    for (int e = e0 + t * 4; e < vend; e += 1024) {
        int4 d = *(const int4*)&dst[e];
        atomicAdd(&h[d.x >> BSHIFT], 1);
        atomicAdd(&h[d.y >> BSHIFT], 1);
        atomicAdd(&h[d.z >> BSHIFT], 1);
        atomicAdd(&h[d.w >> BSHIFT], 1);
    }
    for (int e = vend + t; e < e1; e += 256)
        atomicAdd(&h[dst[e] >> BSHIFT], 1);
    __syncthreads();
    for (int i = t; i < nbin; i += 256)
        res[i] = h[i] ? atomicAdd(&binCur[i], h[i]) : 0;
    __syncthreads();
    for (int i = t; i < nbin; i += 256) h[i] = 0;
    __syncthreads();
    // write pass (same pattern as count pass)
    for (int e = e0 + t * 4; e < vend; e += 1024) {
        int4 d = *(const int4*)&dst[e];
        int4 s = *(const int4*)&src[e];
        int b0 = d.x >> BSHIFT;
        int p0 = res[b0] + atomicAdd(&h[b0], 1);
        tmp[p0] = ((unsigned)s.x << BSHIFT) | (unsigned)(d.x & (BINW - 1));
        int b1 = d.y >> BSHIFT;
        int p1 = res[b1] + atomicAdd(&h[b1], 1);
        tmp[p1] = ((unsigned)s.y << BSHIFT) | (unsigned)(d.y & (BINW - 1));
        int b2 = d.z >> BSHIFT;
        int p2 = res[b2] + atomicAdd(&h[b2], 1);
        tmp[p2] = ((unsigned)s.z << BSHIFT) | (unsigned)(d.z & (BINW - 1));
        int b3 = d.w >> BSHIFT;
        int p3 = res[b3] + atomicAdd(&h[b3], 1);
        tmp[p3] = ((unsigned)s.w << BSHIFT) | (unsigned)(d.w & (BINW - 1));
    }
    for (int e = vend + t; e < e1; e += 256) {
        int d = dst[e];
        int b = d >> BSHIFT;
        int p = res[b] + atomicAdd(&h[b], 1);
        tmp[p] = ((unsigned)src[e] << BSHIFT) | (unsigned)(d & (BINW - 1));
    }
}

__global__ __launch_bounds__(256) void k_csr(const unsigned* __restrict__ tmp,
                                             const int* __restrict__ binBase,
                                             int n, int nbin,
                                             float* __restrict__ dinv,
                                             int* __restrict__ offs,
                                             int* __restrict__ csr) {
    __shared__ int ldeg[BINW];
    __shared__ int loff[BINW];
    __shared__ int pair[256];
    int b = blockIdx.x;
    int t = threadIdx.x;
    ldeg[t] = 0; ldeg[t + 256] = 0;
    __syncthreads();
    int lo = binBase[b], hi = binBase[b + 1];
    for (int p = lo + t; p < hi; p += 256)
        atomicAdd(&ldeg[tmp[p] & (BINW - 1u)], 1);
    __syncthreads();
    int a0 = ldeg[2 * t], a1 = ldeg[2 * t + 1];
    pair[t] = a0 + a1;
    __syncthreads();
    int v = pair[t];
    for (int d = 1; d < 256; d <<= 1) {
        int u = (t >= d) ? pair[t - d] : 0;
        __syncthreads();
        pair[t] += u;
        __syncthreads();
    }
    int ex = pair[t] - v;
    loff[2 * t] = ex;
    loff[2 * t + 1] = ex + a0;
    __syncthreads();
    int v0 = b << BSHIFT;
    for (int i = t; i < BINW; i += 256) {
        int vv = v0 + i;
        if (vv < n) {
            offs[vv] = lo + loff[i];
            dinv[vv] = 1.0f / sqrtf((float)(ldeg[i] + 1));
        }
    }
    if (t == 0 && b == nbin - 1) offs[n] = hi;
    __syncthreads();
    ldeg[t] = 0; ldeg[t + 256] = 0;
    __syncthreads();
    for (int p = lo + t; p < hi; p += 256) {
        unsigned u = tmp[p];
        int d0 = (int)(u & (BINW - 1u));
        int pos = loff[d0] + atomicAdd(&ldeg[d0], 1);
        csr[lo + pos] = (int)(u >> BSHIFT);
    }
}

// ---------------- xs = x * dinv[row] (row-major prescale) ----------------
__global__ __launch_bounds__(256) void k_scale(const float* __restrict__ x,
                                               const float* __restrict__ dinv,
                                               float* __restrict__ xs, int n) {
    int i = blockIdx.x * 256 + threadIdx.x;   // over n*16 float4 groups
    int v = i >> 4;
    if (v >= n) return;
    float4 a = *(const float4*)&x[(size_t)i * 4];
    float dv = dinv[v];
    a.x *= dv; a.y *= dv; a.z *= dv; a.w *= dv;
    *(float4*)&xs[(size_t)i * 4] = a;
}

// ---------------- aggregation (float4 lanes, row-contiguous) ----------------
// One wave per dst row. LPR = W/4 lanes cover the row; G = 64/LPR edges/slot,
// 2 slots. S is pre-scaled by dinv[row]. out = act(dinv[v]*(sum+self) + bias).
template <int W, bool RELU, bool BIAS>
__global__ __launch_bounds__(256) void k_aggv(const float* __restrict__ S,
                                              const float* __restrict__ dinv,
                                              const int* __restrict__ offs,
                                              const int* __restrict__ csr,
                                              const float* __restrict__ bg,
                                              float* __restrict__ Y, int n) {
    constexpr int LPR = W / 4;
    constexpr int G = 64 / LPR;
    int lane = threadIdx.x & 63;
    int wave = threadIdx.x >> 6;
    int v = blockIdx.x * 4 + wave;
    if (v >= n) return;
    int g = lane / LPR;
    int j = lane % LPR;
    float dv = dinv[v];
    float4 acc0 = make_float4(0.f, 0.f, 0.f, 0.f);
    float4 acc1 = make_float4(0.f, 0.f, 0.f, 0.f);
    if (g == 0)
        acc0 = *(const float4*)&S[(size_t)v * W + j * 4];
    int e0 = offs[v], re = offs[v + 1];
    for (int eb = e0; eb < re; eb += 2 * G) {
        int ea = eb + g, ec = eb + G + g;
        if (ea < re) {
            int u = __builtin_nontemporal_load(&csr[ea]);
            float4 a = *(const float4*)&S[(size_t)u * W + j * 4];
            acc0.x += a.x; acc0.y += a.y; acc0.z += a.z; acc0.w += a.w;
        }
        if (ec < re) {
            int u = __builtin_nontemporal_load(&csr[ec]);
            float4 a = *(const float4*)&S[(size_t)u * W + j * 4];
            acc1.x += a.x; acc1.y += a.y; acc1.z += a.z; acc1.w += a.w;
        }
    }
    acc0.x += acc1.x; acc0.y += acc1.y; acc0.z += acc1.z; acc0.w += acc1.w;
#pragma unroll
    for (int d = LPR; d < 64; d <<= 1) {
        acc0.x += __shfl_xor(acc0.x, d);
        acc0.y += __shfl_xor(acc0.y, d);
        acc0.z += __shfl_xor(acc0.z, d);
        acc0.w += __shfl_xor(acc0.w, d);
    }
    if (lane < LPR) {
        float4 r;
        r.x = dv * acc0.x; r.y = dv * acc0.y; r.z = dv * acc0.z; r.w = dv * acc0.w;
        if (BIAS) {
            float4 bv = *(const float4*)&bg[j * 4];
            r.x += bv.x; r.y += bv.y; r.z += bv.z; r.w += bv.w;
        }
        if (RELU) {
            r.x = fmaxf(r.x, 0.f); r.y = fmaxf(r.y, 0.f);
            r.z = fmaxf(r.z, 0.f); r.w = fmaxf(r.w, 0.f);
        }
        *(float4*)&Y[(size_t)v * W + j * 4] = r;
    }
}

// W=16 aggregation with gemm5 fused: h4 = relu(dinv*sum + b4); Y[v] = (h4.W5)*dinv[v]
__global__ __launch_bounds__(256) void k_agg16_gemm5(const float* __restrict__ S,
                                                     const float* __restrict__ dinv,
                                                     const int* __restrict__ offs,
                                                     const int* __restrict__ csr,
                                                     const float* __restrict__ b4,
                                                     const float* __restrict__ W5,
                                                     float* __restrict__ Y, int n) {
    constexpr int W = 16, LPR = 4, G = 16;
    int lane = threadIdx.x & 63;
    int wave = threadIdx.x >> 6;
    int v = blockIdx.x * 4 + wave;
    if (v >= n) return;
    int g = lane / LPR;
    int j = lane % LPR;
    float dv = dinv[v];
    float4 acc0 = make_float4(0.f, 0.f, 0.f, 0.f);
    float4 acc1 = make_float4(0.f, 0.f, 0.f, 0.f);
    if (g == 0) acc0 = *(const float4*)&S[(size_t)v * W + j * 4];
    int e0 = offs[v], re = offs[v + 1];
    for (int eb = e0; eb < re; eb += 2 * G) {
        int ea = eb + g, ec = eb + G + g;
        if (ea < re) {
            int u = csr[ea];
            float4 a = *(const float4*)&S[(size_t)u * W + j * 4];
            acc0.x += a.x; acc0.y += a.y; acc0.z += a.z; acc0.w += a.w;
        }
        if (ec < re) {
            int u = csr[ec];
            float4 a = *(const float4*)&S[(size_t)u * W + j * 4];
            acc1.x += a.x; acc1.y += a.y; acc1.z += a.z; acc1.w += a.w;
        }
    }
    acc0.x += acc1.x; acc0.y += acc1.y; acc0.z += acc1.z; acc0.w += acc1.w;
#pragma unroll
    for (int d = LPR; d < 64; d <<= 1) {
        acc0.x += __shfl_xor(acc0.x, d);
        acc0.y += __shfl_xor(acc0.y, d);
        acc0.z += __shfl_xor(acc0.z, d);
        acc0.w += __shfl_xor(acc0.w, d);
    }
    float4 bv = *(const float4*)&b4[j * 4];
    float4 w5 = *(const float4*)&W5[j * 4];
    float hx = fmaxf(dv * acc0.x + bv.x, 0.f);
    float hy = fmaxf(dv * acc0.y + bv.y, 0.f);
    float hz = fmaxf(dv * acc0.z + bv.z, 0.f);
    float hw = fmaxf(dv * acc0.w + bv.w, 0.f);
    float p = hx * w5.x + hy * w5.y + hz * w5.z + hw * w5.w;
    p += __shfl_xor(p, 1);
    p += __shfl_xor(p, 2);
    if (lane == 0) Y[v] = p * dv;
}

__global__ __launch_bounds__(256) void k_agg1(const float* __restrict__ S,
                                              const float* __restrict__ dinv,
                                              const int* __restrict__ offs,
                                              const int* __restrict__ csr,
                                              const float* __restrict__ bg,
                                              float* __restrict__ Y, int n) {
    int v = blockIdx.x * 256 + threadIdx.x;
    if (v >= n) return;
    float sum = S[v];
    int e = offs[v], re = offs[v + 1];
    for (; e < re; ++e) sum += S[csr[e]];
    Y[v] = dinv[v] * sum + bg[0];
}

// ---------------- tall-skinny GEMMs ----------------
// NR rows per thread. EPI==0: += bias, relu. EPI==1: *= dinv[row].
template <int IN, int OUT, int EPI, int NR>
__global__ __launch_bounds__(256) void k_gemm(const float* __restrict__ X,
                                              const float* __restrict__ Wg,
                                              const float* __restrict__ bg,
                                              const float* __restrict__ dinv,
                                              float* __restrict__ Y, int nrows) {
    constexpr int TPR = OUT / 4;
    constexpr int GROUPS = 256 / TPR;
    constexpr int ROWS = GROUPS * NR;
    __shared__ __align__(16) float Wl[IN * OUT];
    __shared__ __align__(16) float xl[ROWS * IN];
    __shared__ float bl[OUT];
    int tid = threadIdx.x;
    for (int i = tid; i < IN * OUT; i += 256) Wl[i] = Wg[i];
    if (EPI == 0)
        for (int i = tid; i < OUT; i += 256) bl[i] = bg[i];
    int base = blockIdx.x * ROWS;
    for (int i = tid; i < ROWS * IN; i += 256) {
        int r = base + i / IN;
        xl[i] = (r < nrows) ? X[(size_t)base * IN + i] : 0.0f;
    }
    __syncthreads();
    int g = tid / TPR;
    int c0 = (tid % TPR) * 4;
    float4 acc[NR];
#pragma unroll
    for (int r = 0; r < NR; ++r) acc[r] = make_float4(0.f, 0.f, 0.f, 0.f);
#pragma unroll 8
    for (int k = 0; k < IN; ++k) {
        float4 w = *(const float4*)&Wl[k * OUT + c0];
#pragma unroll
        for (int r = 0; r < NR; ++r) {
            float a = xl[(g * NR + r) * IN + k];
            acc[r].x += a * w.x; acc[r].y += a * w.y;
            acc[r].z += a * w.z; acc[r].w += a * w.w;
        }
    }
#pragma unroll
    for (int r = 0; r < NR; ++r) {
        int row = base + g * NR + r;
        if (row >= nrows) continue;
        float4 o = acc[r];
        if (EPI == 0) {
            o.x = fmaxf(o.x + bl[c0], 0.f);
            o.y = fmaxf(o.y + bl[c0 + 1], 0.f);
            o.z = fmaxf(o.z + bl[c0 + 2], 0.f);
            o.w = fmaxf(o.w + bl[c0 + 3], 0.f);
        } else {
            float d0 = dinv[row];
            o.x *= d0; o.y *= d0; o.z *= d0; o.w *= d0;
        }
        *(float4*)&Y[(size_t)row * OUT + c0] = o;
    }
}

extern "C" void kernel_launch(void* const* d_in, const int* in_sizes, int n_in,
                              void* d_out, int out_size, void* d_ws, size_t ws_size,
                              hipStream_t stream) {
    const float* x  = (const float*)d_in[0];
    const int*   ei = (const int*)d_in[1];
    const float* W1 = (const float*)d_in[2];  const float* b1 = (const float*)d_in[3];
    const float* W2 = (const float*)d_in[4];  const float* b2 = (const float*)d_in[5];
    const float* W3 = (const float*)d_in[6];  const float* b3 = (const float*)d_in[7];
    const float* W4 = (const float*)d_in[8];  const float* b4 = (const float*)d_in[9];
    const float* W5 = (const float*)d_in[10]; const float* b5 = (const float*)d_in[11];

    const int N = in_sizes[0] / 64;   // 100000
    const int E = in_sizes[1] / 2;    // 1600000
    const int* src = ei;
    const int* dst = ei + E;
    const int nbin = (N + BINW - 1) / BINW;   // 196

    char* ws = (char*)d_ws;
    size_t off = 0;
    auto alloc = [&](size_t bytes) -> void* {
        void* p = ws + off;
        off = (off + bytes + 255) & ~(size_t)255;
        return p;
    };
    float* dinv    = (float*)alloc((size_t)N * 4);
    int*   offs    = (int*)alloc((size_t)(N + 1) * 4);
    int*   binCnt  = (int*)alloc((size_t)NBIN_MAX * 4);
    int*   binBase = (int*)alloc((size_t)(NBIN_MAX + 1) * 4);
    int*   binCur  = (int*)alloc((size_t)NBIN_MAX * 4);
    int*   csr     = (int*)alloc((size_t)E * 4);
    float* s5      = (float*)alloc((size_t)N * 4);
    float* A       = (float*)alloc((size_t)N * 128 * 4);  // xs -> h1 -> h3
    float* B       = (float*)alloc((size_t)N * 64 * 4);   // agg1/s2/s3/s4
    float* C       = (float*)alloc((size_t)N * 64 * 4);   // tmp -> h2
    unsigned* tmp  = (unsigned*)C;
    float* xs      = A;                                    // dead before GEMM1 writes A

    hipMemsetAsync(binCnt, 0, (size_t)NBIN_MAX * 4, stream);

    k_hist<<<256, 256, 0, stream>>>(dst, E, nbin, binCnt);
    k_binscan<<<1, 256, 0, stream>>>(binCnt, nbin, binBase, binCur);
    k_binfill<<<(E + CHUNK - 1) / CHUNK, 256, 0, stream>>>(src, dst, E, nbin, binCur, tmp);
    k_csr<<<nbin, 256, 0, stream>>>(tmp, binBase, N, nbin, dinv, offs, csr);

    const int gagg = (N + 3) / 4;
    // Layer 1: xs = x*dinv; agg1 = A.x (gathers xs, no per-edge dinv); h1 = relu(agg1@W1+b1)
    k_scale<<<(N * 16 + 255) / 256, 256, 0, stream>>>(x, dinv, xs, N);
    k_aggv<64, false, false><<<gagg, 256, 0, stream>>>(xs, dinv, offs, csr, nullptr, B, N);
    k_gemm<64, 128, 0, 4><<<(N + 31) / 32, 256, 0, stream>>>(B, W1, b1, nullptr, A, N);
    // Layer 2
    k_gemm<128, 64, 1, 2><<<(N + 31) / 32, 256, 0, stream>>>(A, W2, nullptr, dinv, B, N);
    k_aggv<64, true, true><<<gagg, 256, 0, stream>>>(B, dinv, offs, csr, b2, C, N);
    // Layer 3
    k_gemm<64, 32, 1, 2><<<(N + 63) / 64, 256, 0, stream>>>(C, W3, nullptr, dinv, B, N);
    k_aggv<32, true, true><<<gagg, 256, 0, stream>>>(B, dinv, offs, csr, b3, A, N);
    // Layer 4: s4 = (h3@W4)*dinv, fused agg+gemm5 -> s5 (h4 never stored)
    k_gemm<32, 16, 1, 2><<<(N + 127) / 128, 256, 0, stream>>>(A, W4, nullptr, dinv, B, N);
    k_agg16_gemm5<<<gagg, 256, 0, stream>>>(B, dinv, offs, csr, b4, W5, s5, N);
    // Layer 5: out = A.s5 + b5
    k_agg1<<<(N + 255) / 256, 256, 0, stream>>>(s5, dinv, offs, csr, b5, (float*)d_out, N);
}

// Round 9
// 415.320 us; speedup vs baseline: 1.4509x; 1.0804x over previous
//
#include <hip/hip_runtime.h>
#include <math.h>

// GCN 5-layer: per layer relu(A @ (h @ W) + b), A = sym-normalized adj w/ self-loops.
// CSR-by-dst build, aggregate on the narrow side of each GEMM, fold dinv[src]
// row-scaling into GEMM epilogues. All fp32.
// R4: radix build. R5: float4 agg. R6: sliced agg FAILED. R8: xs prescale (neutral).
// Evidence: R5/R6/R8 all run at ~0.13 line-touches/cy/CU regardless of layout and
// L2 residency; VGPR=16 => ~2 outstanding gathers/wave => LATENCY-bound (Little's law
// matches). R9: 4-deep batched gather buffering (16 edges in flight per wave) to
// raise MLP; everything else frozen.

#define NBIN_MAX 256
#define BSHIFT 9
#define BINW 512
#define CHUNK 2048

// ---------------- graph build (radix pipeline) ----------------
__global__ __launch_bounds__(256) void k_hist(const int* __restrict__ dst, int E,
                                              int nbin, int* __restrict__ binCnt) {
    __shared__ int h[NBIN_MAX];
    int t = threadIdx.x;
    for (int i = t; i < nbin; i += 256) h[i] = 0;
    __syncthreads();
    int e4 = (blockIdx.x * 256 + t) * 4;
    int stride = gridDim.x * 256 * 4;
    for (; e4 + 3 < E; e4 += stride) {
        int4 d = *(const int4*)&dst[e4];
        atomicAdd(&h[d.x >> BSHIFT], 1);
        atomicAdd(&h[d.y >> BSHIFT], 1);
        atomicAdd(&h[d.z >> BSHIFT], 1);
        atomicAdd(&h[d.w >> BSHIFT], 1);
    }
    for (; e4 < E; ++e4) atomicAdd(&h[dst[e4] >> BSHIFT], 1);
    __syncthreads();
    for (int i = t; i < nbin; i += 256)
        if (h[i]) atomicAdd(&binCnt[i], h[i]);
}

__global__ __launch_bounds__(256) void k_binscan(const int* __restrict__ binCnt,
                                                 int nbin, int* __restrict__ binBase,
                                                 int* __restrict__ binCur) {
    __shared__ int sh[256];
    int t = threadIdx.x;
    int v = (t < nbin) ? binCnt[t] : 0;
    sh[t] = v;
    __syncthreads();
    for (int d = 1; d < 256; d <<= 1) {
        int u = (t >= d) ? sh[t - d] : 0;
        __syncthreads();
        sh[t] += u;
        __syncthreads();
    }
    int ex = sh[t] - v;
    if (t < nbin) { binBase[t] = ex; binCur[t] = ex; }
    if (t == nbin - 1) binBase[nbin] = sh[t];
}

__global__ __launch_bounds__(256) void k_binfill(const int* __restrict__ src,
                                                 const int* __restrict__ dst, int E,
                                                 int nbin, int* __restrict__ binCur,
                                                 unsigned* __restrict__ tmp) {
    __shared__ int h[NBIN_MAX];
    __shared__ int res[NBIN_MAX];
    int t = threadIdx.x;
    int e0 = blockIdx.x * CHUNK;
    int e1 = min(e0 + CHUNK, E);
    int vend = e0 + ((e1 - e0) & ~3);
    for (int i = t; i < nbin; i += 256) h[i] = 0;
    __syncthreads();
    for (int e = e0 + t * 4; e < vend; e += 1024) {
        int4 d = *(const int4*)&dst[e];
        atomicAdd(&h[d.x >> BSHIFT], 1);
        atomicAdd(&h[d.y >> BSHIFT], 1);
        atomicAdd(&h[d.z >> BSHIFT], 1);
        atomicAdd(&h[d.w >> BSHIFT], 1);
    }
    for (int e = vend + t; e < e1; e += 256)
        atomicAdd(&h[dst[e] >> BSHIFT], 1);
    __syncthreads();
    for (int i = t; i < nbin; i += 256)
        res[i] = h[i] ? atomicAdd(&binCur[i], h[i]) : 0;
    __syncthreads();
    for (int i = t; i < nbin; i += 256) h[i] = 0;
    __syncthreads();
    for (int e = e0 + t * 4; e < vend; e += 1024) {
        int4 d = *(const int4*)&dst[e];
        int4 s = *(const int4*)&src[e];
        int b0 = d.x >> BSHIFT;
        int p0 = res[b0] + atomicAdd(&h[b0], 1);
        tmp[p0] = ((unsigned)s.x << BSHIFT) | (unsigned)(d.x & (BINW - 1));
        int b1 = d.y >> BSHIFT;
        int p1 = res[b1] + atomicAdd(&h[b1], 1);
        tmp[p1] = ((unsigned)s.y << BSHIFT) | (unsigned)(d.y & (BINW - 1));
        int b2 = d.z >> BSHIFT;
        int p2 = res[b2] + atomicAdd(&h[b2], 1);
        tmp[p2] = ((unsigned)s.z << BSHIFT) | (unsigned)(d.z & (BINW - 1));
        int b3 = d.w >> BSHIFT;
        int p3 = res[b3] + atomicAdd(&h[b3], 1);
        tmp[p3] = ((unsigned)s.w << BSHIFT) | (unsigned)(d.w & (BINW - 1));
    }
    for (int e = vend + t; e < e1; e += 256) {
        int d = dst[e];
        int b = d >> BSHIFT;
        int p = res[b] + atomicAdd(&h[b], 1);
        tmp[p] = ((unsigned)src[e] << BSHIFT) | (unsigned)(d & (BINW - 1));
    }
}

__global__ __launch_bounds__(256) void k_csr(const unsigned* __restrict__ tmp,
                                             const int* __restrict__ binBase,
                                             int n, int nbin,
                                             float* __restrict__ dinv,
                                             int* __restrict__ offs,
                                             int* __restrict__ csr) {
    __shared__ int ldeg[BINW];
    __shared__ int loff[BINW];
    __shared__ int pair[256];
    int b = blockIdx.x;
    int t = threadIdx.x;
    ldeg[t] = 0; ldeg[t + 256] = 0;
    __syncthreads();
    int lo = binBase[b], hi = binBase[b + 1];
    for (int p = lo + t; p < hi; p += 256)
        atomicAdd(&ldeg[tmp[p] & (BINW - 1u)], 1);
    __syncthreads();
    int a0 = ldeg[2 * t], a1 = ldeg[2 * t + 1];
    pair[t] = a0 + a1;
    __syncthreads();
    int v = pair[t];
    for (int d = 1; d < 256; d <<= 1) {
        int u = (t >= d) ? pair[t - d] : 0;
        __syncthreads();
        pair[t] += u;
        __syncthreads();
    }
    int ex = pair[t] - v;
    loff[2 * t] = ex;
    loff[2 * t + 1] = ex + a0;
    __syncthreads();
    int v0 = b << BSHIFT;
    for (int i = t; i < BINW; i += 256) {
        int vv = v0 + i;
        if (vv < n) {
            offs[vv] = lo + loff[i];
            dinv[vv] = 1.0f / sqrtf((float)(ldeg[i] + 1));
        }
    }
    if (t == 0 && b == nbin - 1) offs[n] = hi;
    __syncthreads();
    ldeg[t] = 0; ldeg[t + 256] = 0;
    __syncthreads();
    for (int p = lo + t; p < hi; p += 256) {
        unsigned u = tmp[p];
        int d0 = (int)(u & (BINW - 1u));
        int pos = loff[d0] + atomicAdd(&ldeg[d0], 1);
        csr[lo + pos] = (int)(u >> BSHIFT);
    }
}

// ---------------- xs = x * dinv[row] ----------------
__global__ __launch_bounds__(256) void k_scale(const float* __restrict__ x,
                                               const float* __restrict__ dinv,
                                               float* __restrict__ xs, int n) {
    int i = blockIdx.x * 256 + threadIdx.x;
    int v = i >> 4;
    if (v >= n) return;
    float4 a = *(const float4*)&x[(size_t)i * 4];
    float dv = dinv[v];
    a.x *= dv; a.y *= dv; a.z *= dv; a.w *= dv;
    *(float4*)&xs[(size_t)i * 4] = a;
}

// ---------------- aggregation: batched high-MLP gather ----------------
// One wave per dst row. LPR=W/4 lanes cover a row; G=64/LPR edge slots;
// DEPTH buffered loads per slot -> G*DEPTH edges in flight per iteration.
// S pre-scaled by dinv[row]. out = act(dinv[v]*(sum+self) + bias).
template <int W, int DEPTH, bool RELU, bool BIAS>
__global__ __launch_bounds__(256) void k_aggv(const float* __restrict__ S,
                                              const float* __restrict__ dinv,
                                              const int* __restrict__ offs,
                                              const int* __restrict__ csr,
                                              const float* __restrict__ bg,
                                              float* __restrict__ Y, int n) {
    constexpr int LPR = W / 4;
    constexpr int G = 64 / LPR;
    int lane = threadIdx.x & 63;
    int wave = threadIdx.x >> 6;
    int v = blockIdx.x * 4 + wave;
    if (v >= n) return;
    int g = lane / LPR;
    int j = lane % LPR;
    float dv = dinv[v];
    float ax0 = 0.f, ay0 = 0.f, az0 = 0.f, aw0 = 0.f;
    float ax1 = 0.f, ay1 = 0.f, az1 = 0.f, aw1 = 0.f;
    if (g == 0) {
        float4 sv = *(const float4*)&S[(size_t)v * W + j * 4];
        ax0 = sv.x; ay0 = sv.y; az0 = sv.z; aw0 = sv.w;
    }
    int e0 = offs[v], re = offs[v + 1];
    int eb = e0;
    // fast path: full batches of G*DEPTH edges, all loads issued before use
    for (; eb + G * DEPTH <= re; eb += G * DEPTH) {
        int idx[DEPTH];
#pragma unroll
        for (int d = 0; d < DEPTH; ++d)
            idx[d] = __builtin_nontemporal_load(&csr[eb + d * G + g]);
        float4 buf[DEPTH];
#pragma unroll
        for (int d = 0; d < DEPTH; ++d)
            buf[d] = *(const float4*)&S[(size_t)idx[d] * W + j * 4];
#pragma unroll
        for (int d = 0; d < DEPTH; ++d) {
            if (d & 1) { ax1 += buf[d].x; ay1 += buf[d].y; az1 += buf[d].z; aw1 += buf[d].w; }
            else       { ax0 += buf[d].x; ay0 += buf[d].y; az0 += buf[d].z; aw0 += buf[d].w; }
        }
    }
    // tail: one slot-round at a time, guarded
    for (; eb < re; eb += G) {
        int e = eb + g;
        if (e < re) {
            int u = __builtin_nontemporal_load(&csr[e]);
            float4 a = *(const float4*)&S[(size_t)u * W + j * 4];
            ax0 += a.x; ay0 += a.y; az0 += a.z; aw0 += a.w;
        }
    }
    ax0 += ax1; ay0 += ay1; az0 += az1; aw0 += aw1;
#pragma unroll
    for (int d = LPR; d < 64; d <<= 1) {
        ax0 += __shfl_xor(ax0, d);
        ay0 += __shfl_xor(ay0, d);
        az0 += __shfl_xor(az0, d);
        aw0 += __shfl_xor(aw0, d);
    }
    if (lane < LPR) {
        float4 r;
        r.x = dv * ax0; r.y = dv * ay0; r.z = dv * az0; r.w = dv * aw0;
        if (BIAS) {
            float4 bv = *(const float4*)&bg[j * 4];
            r.x += bv.x; r.y += bv.y; r.z += bv.z; r.w += bv.w;
        }
        if (RELU) {
            r.x = fmaxf(r.x, 0.f); r.y = fmaxf(r.y, 0.f);
            r.z = fmaxf(r.z, 0.f); r.w = fmaxf(r.w, 0.f);
        }
        *(float4*)&Y[(size_t)v * W + j * 4] = r;
    }
}

// W=16 aggregation with gemm5 fused: h4 = relu(dinv*sum + b4); Y[v] = (h4.W5)*dinv[v]
__global__ __launch_bounds__(256) void k_agg16_gemm5(const float* __restrict__ S,
                                                     const float* __restrict__ dinv,
                                                     const int* __restrict__ offs,
                                                     const int* __restrict__ csr,
                                                     const float* __restrict__ b4,
                                                     const float* __restrict__ W5,
                                                     float* __restrict__ Y, int n) {
    constexpr int W = 16, LPR = 4, G = 16;
    int lane = threadIdx.x & 63;
    int wave = threadIdx.x >> 6;
    int v = blockIdx.x * 4 + wave;
    if (v >= n) return;
    int g = lane / LPR;
    int j = lane % LPR;
    float dv = dinv[v];
    float4 acc0 = make_float4(0.f, 0.f, 0.f, 0.f);
    float4 acc1 = make_float4(0.f, 0.f, 0.f, 0.f);
    if (g == 0) acc0 = *(const float4*)&S[(size_t)v * W + j * 4];
    int e0 = offs[v], re = offs[v + 1];
    for (int eb = e0; eb < re; eb += 2 * G) {
        int ea = eb + g, ec = eb + G + g;
        if (ea < re) {
            int u = csr[ea];
            float4 a = *(const float4*)&S[(size_t)u * W + j * 4];
            acc0.x += a.x; acc0.y += a.y; acc0.z += a.z; acc0.w += a.w;
        }
        if (ec < re) {
            int u = csr[ec];
            float4 a = *(const float4*)&S[(size_t)u * W + j * 4];
            acc1.x += a.x; acc1.y += a.y; acc1.z += a.z; acc1.w += a.w;
        }
    }
    acc0.x += acc1.x; acc0.y += acc1.y; acc0.z += acc1.z; acc0.w += acc1.w;
#pragma unroll
    for (int d = LPR; d < 64; d <<= 1) {
        acc0.x += __shfl_xor(acc0.x, d);
        acc0.y += __shfl_xor(acc0.y, d);
        acc0.z += __shfl_xor(acc0.z, d);
        acc0.w += __shfl_xor(acc0.w, d);
    }
    float4 bv = *(const float4*)&b4[j * 4];
    float4 w5 = *(const float4*)&W5[j * 4];
    float hx = fmaxf(dv * acc0.x + bv.x, 0.f);
    float hy = fmaxf(dv * acc0.y + bv.y, 0.f);
    float hz = fmaxf(dv * acc0.z + bv.z, 0.f);
    float hw = fmaxf(dv * acc0.w + bv.w, 0.f);
    float p = hx * w5.x + hy * w5.y + hz * w5.z + hw * w5.w;
    p += __shfl_xor(p, 1);
    p += __shfl_xor(p, 2);
    if (lane == 0) Y[v] = p * dv;
}

__global__ __launch_bounds__(256) void k_agg1(const float* __restrict__ S,
                                              const float* __restrict__ dinv,
                                              const int* __restrict__ offs,
                                              const int* __restrict__ csr,
                                              const float* __restrict__ bg,
                                              float* __restrict__ Y, int n) {
    int v = blockIdx.x * 256 + threadIdx.x;
    if (v >= n) return;
    float s0 = S[v], s1 = 0.f, s2 = 0.f, s3 = 0.f;
    int e = offs[v], re = offs[v + 1];
    for (; e + 4 <= re; e += 4) {
        int i0 = csr[e], i1 = csr[e + 1], i2 = csr[e + 2], i3 = csr[e + 3];
        s0 += S[i0]; s1 += S[i1]; s2 += S[i2]; s3 += S[i3];
    }
    for (; e < re; ++e) s0 += S[csr[e]];
    Y[v] = dinv[v] * ((s0 + s1) + (s2 + s3)) + bg[0];
}

// ---------------- tall-skinny GEMMs ----------------
template <int IN, int OUT, int EPI, int NR>
__global__ __launch_bounds__(256) void k_gemm(const float* __restrict__ X,
                                              const float* __restrict__ Wg,
                                              const float* __restrict__ bg,
                                              const float* __restrict__ dinv,
                                              float* __restrict__ Y, int nrows) {
    constexpr int TPR = OUT / 4;
    constexpr int GROUPS = 256 / TPR;
    constexpr int ROWS = GROUPS * NR;
    __shared__ __align__(16) float Wl[IN * OUT];
    __shared__ __align__(16) float xl[ROWS * IN];
    __shared__ float bl[OUT];
    int tid = threadIdx.x;
    for (int i = tid; i < IN * OUT; i += 256) Wl[i] = Wg[i];
    if (EPI == 0)
        for (int i = tid; i < OUT; i += 256) bl[i] = bg[i];
    int base = blockIdx.x * ROWS;
    for (int i = tid; i < ROWS * IN; i += 256) {
        int r = base + i / IN;
        xl[i] = (r < nrows) ? X[(size_t)base * IN + i] : 0.0f;
    }
    __syncthreads();
    int g = tid / TPR;
    int c0 = (tid % TPR) * 4;
    float4 acc[NR];
#pragma unroll
    for (int r = 0; r < NR; ++r) acc[r] = make_float4(0.f, 0.f, 0.f, 0.f);
#pragma unroll 8
    for (int k = 0; k < IN; ++k) {
        float4 w = *(const float4*)&Wl[k * OUT + c0];
#pragma unroll
        for (int r = 0; r < NR; ++r) {
            float a = xl[(g * NR + r) * IN + k];
            acc[r].x += a * w.x; acc[r].y += a * w.y;
            acc[r].z += a * w.z; acc[r].w += a * w.w;
        }
    }
#pragma unroll
    for (int r = 0; r < NR; ++r) {
        int row = base + g * NR + r;
        if (row >= nrows) continue;
        float4 o = acc[r];
        if (EPI == 0) {
            o.x = fmaxf(o.x + bl[c0], 0.f);
            o.y = fmaxf(o.y + bl[c0 + 1], 0.f);
            o.z = fmaxf(o.z + bl[c0 + 2], 0.f);
            o.w = fmaxf(o.w + bl[c0 + 3], 0.f);
        } else {
            float d0 = dinv[row];
            o.x *= d0; o.y *= d0; o.z *= d0; o.w *= d0;
        }
        *(float4*)&Y[(size_t)row * OUT + c0] = o;
    }
}

extern "C" void kernel_launch(void* const* d_in, const int* in_sizes, int n_in,
                              void* d_out, int out_size, void* d_ws, size_t ws_size,
                              hipStream_t stream) {
    const float* x  = (const float*)d_in[0];
    const int*   ei = (const int*)d_in[1];
    const float* W1 = (const float*)d_in[2];  const float* b1 = (const float*)d_in[3];
    const float* W2 = (const float*)d_in[4];  const float* b2 = (const float*)d_in[5];
    const float* W3 = (const float*)d_in[6];  const float* b3 = (const float*)d_in[7];
    const float* W4 = (const float*)d_in[8];  const float* b4 = (const float*)d_in[9];
    const float* W5 = (const float*)d_in[10]; const float* b5 = (const float*)d_in[11];

    const int N = in_sizes[0] / 64;   // 100000
    const int E = in_sizes[1] / 2;    // 1600000
    const int* src = ei;
    const int* dst = ei + E;
    const int nbin = (N + BINW - 1) / BINW;   // 196

    char* ws = (char*)d_ws;
    size_t off = 0;
    auto alloc = [&](size_t bytes) -> void* {
        void* p = ws + off;
        off = (off + bytes + 255) & ~(size_t)255;
        return p;
    };
    float* dinv    = (float*)alloc((size_t)N * 4);
    int*   offs    = (int*)alloc((size_t)(N + 1) * 4);
    int*   binCnt  = (int*)alloc((size_t)NBIN_MAX * 4);
    int*   binBase = (int*)alloc((size_t)(NBIN_MAX + 1) * 4);
    int*   binCur  = (int*)alloc((size_t)NBIN_MAX * 4);
    int*   csr     = (int*)alloc((size_t)E * 4);
    float* s5      = (float*)alloc((size_t)N * 4);
    float* A       = (float*)alloc((size_t)N * 128 * 4);  // xs -> h1 -> h3
    float* B       = (float*)alloc((size_t)N * 64 * 4);   // agg1/s2/s3/s4
    float* C       = (float*)alloc((size_t)N * 64 * 4);   // tmp -> h2
    unsigned* tmp  = (unsigned*)C;
    float* xs      = A;                                    // dead before GEMM1 writes A

    hipMemsetAsync(binCnt, 0, (size_t)NBIN_MAX * 4, stream);

    k_hist<<<256, 256, 0, stream>>>(dst, E, nbin, binCnt);
    k_binscan<<<1, 256, 0, stream>>>(binCnt, nbin, binBase, binCur);
    k_binfill<<<(E + CHUNK - 1) / CHUNK, 256, 0, stream>>>(src, dst, E, nbin, binCur, tmp);
    k_csr<<<nbin, 256, 0, stream>>>(tmp, binBase, N, nbin, dinv, offs, csr);

    const int gagg = (N + 3) / 4;
    // Layer 1: xs = x*dinv; agg1 = A.x; h1 = relu(agg1@W1+b1)
    k_scale<<<(N * 16 + 255) / 256, 256, 0, stream>>>(x, dinv, xs, N);
    k_aggv<64, 4, false, false><<<gagg, 256, 0, stream>>>(xs, dinv, offs, csr, nullptr, B, N);
    k_gemm<64, 128, 0, 4><<<(N + 31) / 32, 256, 0, stream>>>(B, W1, b1, nullptr, A, N);
    // Layer 2
    k_gemm<128, 64, 1, 2><<<(N + 31) / 32, 256, 0, stream>>>(A, W2, nullptr, dinv, B, N);
    k_aggv<64, 4, true, true><<<gagg, 256, 0, stream>>>(B, dinv, offs, csr, b2, C, N);
    // Layer 3
    k_gemm<64, 32, 1, 2><<<(N + 63) / 64, 256, 0, stream>>>(C, W3, nullptr, dinv, B, N);
    k_aggv<32, 2, true, true><<<gagg, 256, 0, stream>>>(B, dinv, offs, csr, b3, A, N);
    // Layer 4: s4 = (h3@W4)*dinv, fused agg+gemm5 -> s5 (h4 never stored)
    k_gemm<32, 16, 1, 2><<<(N + 127) / 128, 256, 0, stream>>>(A, W4, nullptr, dinv, B, N);
    k_agg16_gemm5<<<gagg, 256, 0, stream>>>(B, dinv, offs, csr, b4, W5, s5, N);
    // Layer 5: out = A.s5 + b5
    k_agg1<<<(N + 255) / 256, 256, 0, stream>>>(s5, dinv, offs, csr, b5, (float*)d_out, N);
}

// Round 10
// 412.761 us; speedup vs baseline: 1.4599x; 1.0062x over previous
//
#include <hip/hip_runtime.h>
#include <math.h>

// GCN 5-layer: per layer relu(A @ (h @ W) + b), A = sym-normalized adj w/ self-loops.
// CSR-by-dst build, aggregate on the narrow side of each GEMM, fold dinv[src]
// row-scaling into GEMM epilogues. All fp32.
// R4: radix build. R5: float4 agg. R6: sliced agg FAILED (line touches 2x).
// R8: xs prescale NEUTRAL in-kernel, -10us by dropping the extra pass (reverted here).
// R9: 4-deep batching: 79->67us, fetch 2.9->3.4TB/s, but VGPR only 24 (compiler
//     re-serialized loads). R10: pipelined idx prefetch + sched_barrier(0) fence to
//     force all DEPTH gathers in flight (VGPR-resident); layer1 gathers x/dinv direct.

#define NBIN_MAX 256
#define BSHIFT 9
#define BINW 512
#define CHUNK 2048

// ---------------- graph build (radix pipeline) ----------------
__global__ __launch_bounds__(256) void k_hist(const int* __restrict__ dst, int E,
                                              int nbin, int* __restrict__ binCnt) {
    __shared__ int h[NBIN_MAX];
    int t = threadIdx.x;
    for (int i = t; i < nbin; i += 256) h[i] = 0;
    __syncthreads();
    int e4 = (blockIdx.x * 256 + t) * 4;
    int stride = gridDim.x * 256 * 4;
    for (; e4 + 3 < E; e4 += stride) {
        int4 d = *(const int4*)&dst[e4];
        atomicAdd(&h[d.x >> BSHIFT], 1);
        atomicAdd(&h[d.y >> BSHIFT], 1);
        atomicAdd(&h[d.z >> BSHIFT], 1);
        atomicAdd(&h[d.w >> BSHIFT], 1);
    }
    for (; e4 < E; ++e4) atomicAdd(&h[dst[e4] >> BSHIFT], 1);
    __syncthreads();
    for (int i = t; i < nbin; i += 256)
        if (h[i]) atomicAdd(&binCnt[i], h[i]);
}

__global__ __launch_bounds__(256) void k_binscan(const int* __restrict__ binCnt,
                                                 int nbin, int* __restrict__ binBase,
                                                 int* __restrict__ binCur) {
    __shared__ int sh[256];
    int t = threadIdx.x;
    int v = (t < nbin) ? binCnt[t] : 0;
    sh[t] = v;
    __syncthreads();
    for (int d = 1; d < 256; d <<= 1) {
        int u = (t >= d) ? sh[t - d] : 0;
        __syncthreads();
        sh[t] += u;
        __syncthreads();
    }
    int ex = sh[t] - v;
    if (t < nbin) { binBase[t] = ex; binCur[t] = ex; }
    if (t == nbin - 1) binBase[nbin] = sh[t];
}

__global__ __launch_bounds__(256) void k_binfill(const int* __restrict__ src,
                                                 const int* __restrict__ dst, int E,
                                                 int nbin, int* __restrict__ binCur,
                                                 unsigned* __restrict__ tmp) {
    __shared__ int h[NBIN_MAX];
    __shared__ int res[NBIN_MAX];
    int t = threadIdx.x;
    int e0 = blockIdx.x * CHUNK;
    int e1 = min(e0 + CHUNK, E);
    int vend = e0 + ((e1 - e0) & ~3);
    for (int i = t; i < nbin; i += 256) h[i] = 0;
    __syncthreads();
    for (int e = e0 + t * 4; e < vend; e += 1024) {
        int4 d = *(const int4*)&dst[e];
        atomicAdd(&h[d.x >> BSHIFT], 1);
        atomicAdd(&h[d.y >> BSHIFT], 1);
        atomicAdd(&h[d.z >> BSHIFT], 1);
        atomicAdd(&h[d.w >> BSHIFT], 1);
    }
    for (int e = vend + t; e < e1; e += 256)
        atomicAdd(&h[dst[e] >> BSHIFT], 1);
    __syncthreads();
    for (int i = t; i < nbin; i += 256)
        res[i] = h[i] ? atomicAdd(&binCur[i], h[i]) : 0;
    __syncthreads();
    for (int i = t; i < nbin; i += 256) h[i] = 0;
    __syncthreads();
    for (int e = e0 + t * 4; e < vend; e += 1024) {
        int4 d = *(const int4*)&dst[e];
        int4 s = *(const int4*)&src[e];
        int b0 = d.x >> BSHIFT;
        int p0 = res[b0] + atomicAdd(&h[b0], 1);
        tmp[p0] = ((unsigned)s.x << BSHIFT) | (unsigned)(d.x & (BINW - 1));
        int b1 = d.y >> BSHIFT;
        int p1 = res[b1] + atomicAdd(&h[b1], 1);
        tmp[p1] = ((unsigned)s.y << BSHIFT) | (unsigned)(d.y & (BINW - 1));
        int b2 = d.z >> BSHIFT;
        int p2 = res[b2] + atomicAdd(&h[b2], 1);
        tmp[p2] = ((unsigned)s.z << BSHIFT) | (unsigned)(d.z & (BINW - 1));
        int b3 = d.w >> BSHIFT;
        int p3 = res[b3] + atomicAdd(&h[b3], 1);
        tmp[p3] = ((unsigned)s.w << BSHIFT) | (unsigned)(d.w & (BINW - 1));
    }
    for (int e = vend + t; e < e1; e += 256) {
        int d = dst[e];
        int b = d >> BSHIFT;
        int p = res[b] + atomicAdd(&h[b], 1);
        tmp[p] = ((unsigned)src[e] << BSHIFT) | (unsigned)(d & (BINW - 1));
    }
}

__global__ __launch_bounds__(256) void k_csr(const unsigned* __restrict__ tmp,
                                             const int* __restrict__ binBase,
                                             int n, int nbin,
                                             float* __restrict__ dinv,
                                             int* __restrict__ offs,
                                             int* __restrict__ csr) {
    __shared__ int ldeg[BINW];
    __shared__ int loff[BINW];
    __shared__ int pair[256];
    int b = blockIdx.x;
    int t = threadIdx.x;
    ldeg[t] = 0; ldeg[t + 256] = 0;
    __syncthreads();
    int lo = binBase[b], hi = binBase[b + 1];
    for (int p = lo + t; p < hi; p += 256)
        atomicAdd(&ldeg[tmp[p] & (BINW - 1u)], 1);
    __syncthreads();
    int a0 = ldeg[2 * t], a1 = ldeg[2 * t + 1];
    pair[t] = a0 + a1;
    __syncthreads();
    int v = pair[t];
    for (int d = 1; d < 256; d <<= 1) {
        int u = (t >= d) ? pair[t - d] : 0;
        __syncthreads();
        pair[t] += u;
        __syncthreads();
    }
    int ex = pair[t] - v;
    loff[2 * t] = ex;
    loff[2 * t + 1] = ex + a0;
    __syncthreads();
    int v0 = b << BSHIFT;
    for (int i = t; i < BINW; i += 256) {
        int vv = v0 + i;
        if (vv < n) {
            offs[vv] = lo + loff[i];
            dinv[vv] = 1.0f / sqrtf((float)(ldeg[i] + 1));
        }
    }
    if (t == 0 && b == nbin - 1) offs[n] = hi;
    __syncthreads();
    ldeg[t] = 0; ldeg[t + 256] = 0;
    __syncthreads();
    for (int p = lo + t; p < hi; p += 256) {
        unsigned u = tmp[p];
        int d0 = (int)(u & (BINW - 1u));
        int pos = loff[d0] + atomicAdd(&ldeg[d0], 1);
        csr[lo + pos] = (int)(u >> BSHIFT);
    }
}

// ---------------- aggregation: pipelined, fence-forced high-MLP gather ----------------
// One wave per dst row. LPR=W/4 lanes cover a row; G=64/LPR edge slots;
// DEPTH buffered gathers per slot; idx for batch k+1 prefetched during batch k;
// sched_barrier(0) keeps the gather cluster intact (all DEPTH loads in flight).
// L1S: gather S[u]*dinv[u] (layer 1, S unscaled); else S pre-scaled by dinv[row].
// out = act(dinv[v]*(sum+self) + bias)
template <int W, int DEPTH, bool RELU, bool BIAS, bool L1S>
__global__ __launch_bounds__(256) void k_aggv(const float* __restrict__ S,
                                              const float* __restrict__ dinv,
                                              const int* __restrict__ offs,
                                              const int* __restrict__ csr,
                                              const float* __restrict__ bg,
                                              float* __restrict__ Y, int n) {
    constexpr int LPR = W / 4;
    constexpr int G = 64 / LPR;
    int lane = threadIdx.x & 63;
    int wave = threadIdx.x >> 6;
    int v = blockIdx.x * 4 + wave;
    if (v >= n) return;
    int g = lane / LPR;
    int j = lane % LPR;
    float dv = dinv[v];
    float ax0 = 0.f, ay0 = 0.f, az0 = 0.f, aw0 = 0.f;
    float ax1 = 0.f, ay1 = 0.f, az1 = 0.f, aw1 = 0.f;
    if (g == 0) {
        float4 sv = *(const float4*)&S[(size_t)v * W + j * 4];
        float sc = L1S ? dv : 1.0f;
        ax0 = sv.x * sc; ay0 = sv.y * sc; az0 = sv.z * sc; aw0 = sv.w * sc;
    }
    int e0 = offs[v], re = offs[v + 1];
    int eb = e0;
    int nfull = (re - e0) / (G * DEPTH);
    if (nfull > 0) {
        int idx[DEPTH];
#pragma unroll
        for (int d = 0; d < DEPTH; ++d)
            idx[d] = __builtin_nontemporal_load(&csr[eb + d * G + g]);
        for (int b = 1; b <= nfull; ++b) {
            float4 buf[DEPTH];
            float dsc[DEPTH];
#pragma unroll
            for (int d = 0; d < DEPTH; ++d) {
                buf[d] = *(const float4*)&S[(size_t)idx[d] * W + j * 4];
                if (L1S) dsc[d] = dinv[idx[d]];
            }
            __builtin_amdgcn_sched_barrier(0);   // keep gather cluster intact
            int eb2 = eb + G * DEPTH;
            if (b < nfull) {
#pragma unroll
                for (int d = 0; d < DEPTH; ++d)   // prefetch next batch's indices
                    idx[d] = __builtin_nontemporal_load(&csr[eb2 + d * G + g]);
            }
#pragma unroll
            for (int d = 0; d < DEPTH; ++d) {
                float sc = L1S ? dsc[d] : 1.0f;
                if (d & 1) { ax1 += buf[d].x * sc; ay1 += buf[d].y * sc;
                             az1 += buf[d].z * sc; aw1 += buf[d].w * sc; }
                else       { ax0 += buf[d].x * sc; ay0 += buf[d].y * sc;
                             az0 += buf[d].z * sc; aw0 += buf[d].w * sc; }
            }
            eb = eb2;
        }
    }
    for (; eb < re; eb += G) {                   // guarded tail
        int e = eb + g;
        if (e < re) {
            int u = __builtin_nontemporal_load(&csr[e]);
            float4 a = *(const float4*)&S[(size_t)u * W + j * 4];
            float sc = L1S ? dinv[u] : 1.0f;
            ax0 += a.x * sc; ay0 += a.y * sc; az0 += a.z * sc; aw0 += a.w * sc;
        }
    }
    ax0 += ax1; ay0 += ay1; az0 += az1; aw0 += aw1;
#pragma unroll
    for (int d = LPR; d < 64; d <<= 1) {
        ax0 += __shfl_xor(ax0, d);
        ay0 += __shfl_xor(ay0, d);
        az0 += __shfl_xor(az0, d);
        aw0 += __shfl_xor(aw0, d);
    }
    if (lane < LPR) {
        float4 r;
        r.x = dv * ax0; r.y = dv * ay0; r.z = dv * az0; r.w = dv * aw0;
        if (BIAS) {
            float4 bv = *(const float4*)&bg[j * 4];
            r.x += bv.x; r.y += bv.y; r.z += bv.z; r.w += bv.w;
        }
        if (RELU) {
            r.x = fmaxf(r.x, 0.f); r.y = fmaxf(r.y, 0.f);
            r.z = fmaxf(r.z, 0.f); r.w = fmaxf(r.w, 0.f);
        }
        *(float4*)&Y[(size_t)v * W + j * 4] = r;
    }
}

// W=16 aggregation with gemm5 fused: h4 = relu(dinv*sum + b4); Y[v] = (h4.W5)*dinv[v]
__global__ __launch_bounds__(256) void k_agg16_gemm5(const float* __restrict__ S,
                                                     const float* __restrict__ dinv,
                                                     const int* __restrict__ offs,
                                                     const int* __restrict__ csr,
                                                     const float* __restrict__ b4,
                                                     const float* __restrict__ W5,
                                                     float* __restrict__ Y, int n) {
    constexpr int W = 16, LPR = 4, G = 16;
    int lane = threadIdx.x & 63;
    int wave = threadIdx.x >> 6;
    int v = blockIdx.x * 4 + wave;
    if (v >= n) return;
    int g = lane / LPR;
    int j = lane % LPR;
    float dv = dinv[v];
    float4 acc0 = make_float4(0.f, 0.f, 0.f, 0.f);
    float4 acc1 = make_float4(0.f, 0.f, 0.f, 0.f);
    if (g == 0) acc0 = *(const float4*)&S[(size_t)v * W + j * 4];
    int e0 = offs[v], re = offs[v + 1];
    int eb = e0;
    for (; eb + 2 * G <= re; eb += 2 * G) {      // unguarded full rounds
        int u0 = __builtin_nontemporal_load(&csr[eb + g]);
        int u1 = __builtin_nontemporal_load(&csr[eb + G + g]);
        float4 a0 = *(const float4*)&S[(size_t)u0 * W + j * 4];
        float4 a1 = *(const float4*)&S[(size_t)u1 * W + j * 4];
        __builtin_amdgcn_sched_barrier(0);
        acc0.x += a0.x; acc0.y += a0.y; acc0.z += a0.z; acc0.w += a0.w;
        acc1.x += a1.x; acc1.y += a1.y; acc1.z += a1.z; acc1.w += a1.w;
    }
    for (; eb < re; eb += G) {
        int e = eb + g;
        if (e < re) {
            int u = __builtin_nontemporal_load(&csr[e]);
            float4 a = *(const float4*)&S[(size_t)u * W + j * 4];
            acc0.x += a.x; acc0.y += a.y; acc0.z += a.z; acc0.w += a.w;
        }
    }
    acc0.x += acc1.x; acc0.y += acc1.y; acc0.z += acc1.z; acc0.w += acc1.w;
#pragma unroll
    for (int d = LPR; d < 64; d <<= 1) {
        acc0.x += __shfl_xor(acc0.x, d);
        acc0.y += __shfl_xor(acc0.y, d);
        acc0.z += __shfl_xor(acc0.z, d);
        acc0.w += __shfl_xor(acc0.w, d);
    }
    float4 bv = *(const float4*)&b4[j * 4];
    float4 w5 = *(const float4*)&W5[j * 4];
    float hx = fmaxf(dv * acc0.x + bv.x, 0.f);
    float hy = fmaxf(dv * acc0.y + bv.y, 0.f);
    float hz = fmaxf(dv * acc0.z + bv.z, 0.f);
    float hw = fmaxf(dv * acc0.w + bv.w, 0.f);
    float p = hx * w5.x + hy * w5.y + hz * w5.z + hw * w5.w;
    p += __shfl_xor(p, 1);
    p += __shfl_xor(p, 2);
    if (lane == 0) Y[v] = p * dv;
}

__global__ __launch_bounds__(256) void k_agg1(const float* __restrict__ S,
                                              const float* __restrict__ dinv,
                                              const int* __restrict__ offs,
                                              const int* __restrict__ csr,
                                              const float* __restrict__ bg,
                                              float* __restrict__ Y, int n) {
    int v = blockIdx.x * 256 + threadIdx.x;
    if (v >= n) return;
    float s0 = S[v], s1 = 0.f, s2 = 0.f, s3 = 0.f;
    int e = offs[v], re = offs[v + 1];
    for (; e + 4 <= re; e += 4) {
        int i0 = csr[e], i1 = csr[e + 1], i2 = csr[e + 2], i3 = csr[e + 3];
        s0 += S[i0]; s1 += S[i1]; s2 += S[i2]; s3 += S[i3];
    }
    for (; e < re; ++e) s0 += S[csr[e]];
    Y[v] = dinv[v] * ((s0 + s1) + (s2 + s3)) + bg[0];
}

// ---------------- tall-skinny GEMMs ----------------
template <int IN, int OUT, int EPI, int NR>
__global__ __launch_bounds__(256) void k_gemm(const float* __restrict__ X,
                                              const float* __restrict__ Wg,
                                              const float* __restrict__ bg,
                                              const float* __restrict__ dinv,
                                              float* __restrict__ Y, int nrows) {
    constexpr int TPR = OUT / 4;
    constexpr int GROUPS = 256 / TPR;
    constexpr int ROWS = GROUPS * NR;
    __shared__ __align__(16) float Wl[IN * OUT];
    __shared__ __align__(16) float xl[ROWS * IN];
    __shared__ float bl[OUT];
    int tid = threadIdx.x;
    for (int i = tid; i < IN * OUT; i += 256) Wl[i] = Wg[i];
    if (EPI == 0)
        for (int i = tid; i < OUT; i += 256) bl[i] = bg[i];
    int base = blockIdx.x * ROWS;
    for (int i = tid; i < ROWS * IN; i += 256) {
        int r = base + i / IN;
        xl[i] = (r < nrows) ? X[(size_t)base * IN + i] : 0.0f;
    }
    __syncthreads();
    int g = tid / TPR;
    int c0 = (tid % TPR) * 4;
    float4 acc[NR];
#pragma unroll
    for (int r = 0; r < NR; ++r) acc[r] = make_float4(0.f, 0.f, 0.f, 0.f);
#pragma unroll 8
    for (int k = 0; k < IN; ++k) {
        float4 w = *(const float4*)&Wl[k * OUT + c0];
#pragma unroll
        for (int r = 0; r < NR; ++r) {
            float a = xl[(g * NR + r) * IN + k];
            acc[r].x += a * w.x; acc[r].y += a * w.y;
            acc[r].z += a * w.z; acc[r].w += a * w.w;
        }
    }
#pragma unroll
    for (int r = 0; r < NR; ++r) {
        int row = base + g * NR + r;
        if (row >= nrows) continue;
        float4 o = acc[r];
        if (EPI == 0) {
            o.x = fmaxf(o.x + bl[c0], 0.f);
            o.y = fmaxf(o.y + bl[c0 + 1], 0.f);
            o.z = fmaxf(o.z + bl[c0 + 2], 0.f);
            o.w = fmaxf(o.w + bl[c0 + 3], 0.f);
        } else {
            float d0 = dinv[row];
            o.x *= d0; o.y *= d0; o.z *= d0; o.w *= d0;
        }
        *(float4*)&Y[(size_t)row * OUT + c0] = o;
    }
}

extern "C" void kernel_launch(void* const* d_in, const int* in_sizes, int n_in,
                              void* d_out, int out_size, void* d_ws, size_t ws_size,
                              hipStream_t stream) {
    const float* x  = (const float*)d_in[0];
    const int*   ei = (const int*)d_in[1];
    const float* W1 = (const float*)d_in[2];  const float* b1 = (const float*)d_in[3];
    const float* W2 = (const float*)d_in[4];  const float* b2 = (const float*)d_in[5];
    const float* W3 = (const float*)d_in[6];  const float* b3 = (const float*)d_in[7];
    const float* W4 = (const float*)d_in[8];  const float* b4 = (const float*)d_in[9];
    const float* W5 = (const float*)d_in[10]; const float* b5 = (const float*)d_in[11];

    const int N = in_sizes[0] / 64;   // 100000
    const int E = in_sizes[1] / 2;    // 1600000
    const int* src = ei;
    const int* dst = ei + E;
    const int nbin = (N + BINW - 1) / BINW;   // 196

    char* ws = (char*)d_ws;
    size_t off = 0;
    auto alloc = [&](size_t bytes) -> void* {
        void* p = ws + off;
        off = (off + bytes + 255) & ~(size_t)255;
        return p;
    };
    float* dinv    = (float*)alloc((size_t)N * 4);
    int*   offs    = (int*)alloc((size_t)(N + 1) * 4);
    int*   binCnt  = (int*)alloc((size_t)NBIN_MAX * 4);
    int*   binBase = (int*)alloc((size_t)(NBIN_MAX + 1) * 4);
    int*   binCur  = (int*)alloc((size_t)NBIN_MAX * 4);
    int*   csr     = (int*)alloc((size_t)E * 4);
    float* s5      = (float*)alloc((size_t)N * 4);
    float* A       = (float*)alloc((size_t)N * 128 * 4);  // h1 -> h3
    float* B       = (float*)alloc((size_t)N * 64 * 4);   // agg1/s2/s3/s4
    float* C       = (float*)alloc((size_t)N * 64 * 4);   // tmp -> h2
    unsigned* tmp  = (unsigned*)C;

    hipMemsetAsync(binCnt, 0, (size_t)NBIN_MAX * 4, stream);

    k_hist<<<256, 256, 0, stream>>>(dst, E, nbin, binCnt);
    k_binscan<<<1, 256, 0, stream>>>(binCnt, nbin, binBase, binCur);
    k_binfill<<<(E + CHUNK - 1) / CHUNK, 256, 0, stream>>>(src, dst, E, nbin, binCur, tmp);
    k_csr<<<nbin, 256, 0, stream>>>(tmp, binBase, N, nbin, dinv, offs, csr);

    const int gagg = (N + 3) / 4;
    // Layer 1: agg1 = A.x (per-edge dinv gather, no prescale pass); h1 = relu(agg1@W1+b1)
    k_aggv<64, 4, false, false, true><<<gagg, 256, 0, stream>>>(x, dinv, offs, csr, nullptr, B, N);
    k_gemm<64, 128, 0, 4><<<(N + 31) / 32, 256, 0, stream>>>(B, W1, b1, nullptr, A, N);
    // Layer 2
    k_gemm<128, 64, 1, 2><<<(N + 31) / 32, 256, 0, stream>>>(A, W2, nullptr, dinv, B, N);
    k_aggv<64, 4, true, true, false><<<gagg, 256, 0, stream>>>(B, dinv, offs, csr, b2, C, N);
    // Layer 3
    k_gemm<64, 32, 1, 2><<<(N + 63) / 64, 256, 0, stream>>>(C, W3, nullptr, dinv, B, N);
    k_aggv<32, 2, true, true, false><<<gagg, 256, 0, stream>>>(B, dinv, offs, csr, b3, A, N);
    // Layer 4: s4 = (h3@W4)*dinv, fused agg+gemm5 -> s5 (h4 never stored)
    k_gemm<32, 16, 1, 2><<<(N + 127) / 128, 256, 0, stream>>>(A, W4, nullptr, dinv, B, N);
    k_agg16_gemm5<<<gagg, 256, 0, stream>>>(B, dinv, offs, csr, b4, W5, s5, N);
    // Layer 5: out = A.s5 + b5
    k_agg1<<<(N + 255) / 256, 256, 0, stream>>>(s5, dinv, offs, csr, b5, (float*)d_out, N);
}

// Round 11
// 391.104 us; speedup vs baseline: 1.5407x; 1.0554x over previous
//
#include <hip/hip_runtime.h>
#include <math.h>

// GCN 5-layer: per layer relu(A @ (h @ W) + b), A = sym-normalized adj w/ self-loops.
// CSR-by-dst build, aggregate on the narrow side of each GEMM, fold dinv[src]
// row-scaling into GEMM epilogues. All fp32.
// R4: radix build. R5-R10 agg history: row-per-wave float4 gathers plateau at
// 2.9-3.4 TB/s, latency-bound (VGPR<=28 => ~2-3 lines in flight/wave); G=4 slots x
// avg degree 17 => pipeline batches never form. R11: group-owns-row shape — 16-lane
// groups own one row each, DEPTH-deep double-buffered gathers, no cross-lane reduce.

#define NBIN_MAX 256
#define BSHIFT 9
#define BINW 512
#define CHUNK 2048

// ---------------- graph build (radix pipeline) ----------------
__global__ __launch_bounds__(256) void k_hist(const int* __restrict__ dst, int E,
                                              int nbin, int* __restrict__ binCnt) {
    __shared__ int h[NBIN_MAX];
    int t = threadIdx.x;
    for (int i = t; i < nbin; i += 256) h[i] = 0;
    __syncthreads();
    int e4 = (blockIdx.x * 256 + t) * 4;
    int stride = gridDim.x * 256 * 4;
    for (; e4 + 3 < E; e4 += stride) {
        int4 d = *(const int4*)&dst[e4];
        atomicAdd(&h[d.x >> BSHIFT], 1);
        atomicAdd(&h[d.y >> BSHIFT], 1);
        atomicAdd(&h[d.z >> BSHIFT], 1);
        atomicAdd(&h[d.w >> BSHIFT], 1);
    }
    for (; e4 < E; ++e4) atomicAdd(&h[dst[e4] >> BSHIFT], 1);
    __syncthreads();
    for (int i = t; i < nbin; i += 256)
        if (h[i]) atomicAdd(&binCnt[i], h[i]);
}

__global__ __launch_bounds__(256) void k_binscan(const int* __restrict__ binCnt,
                                                 int nbin, int* __restrict__ binBase,
                                                 int* __restrict__ binCur) {
    __shared__ int sh[256];
    int t = threadIdx.x;
    int v = (t < nbin) ? binCnt[t] : 0;
    sh[t] = v;
    __syncthreads();
    for (int d = 1; d < 256; d <<= 1) {
        int u = (t >= d) ? sh[t - d] : 0;
        __syncthreads();
        sh[t] += u;
        __syncthreads();
    }
    int ex = sh[t] - v;
    if (t < nbin) { binBase[t] = ex; binCur[t] = ex; }
    if (t == nbin - 1) binBase[nbin] = sh[t];
}

__global__ __launch_bounds__(256) void k_binfill(const int* __restrict__ src,
                                                 const int* __restrict__ dst, int E,
                                                 int nbin, int* __restrict__ binCur,
                                                 unsigned* __restrict__ tmp) {
    __shared__ int h[NBIN_MAX];
    __shared__ int res[NBIN_MAX];
    int t = threadIdx.x;
    int e0 = blockIdx.x * CHUNK;
    int e1 = min(e0 + CHUNK, E);
    int vend = e0 + ((e1 - e0) & ~3);
    for (int i = t; i < nbin; i += 256) h[i] = 0;
    __syncthreads();
    for (int e = e0 + t * 4; e < vend; e += 1024) {
        int4 d = *(const int4*)&dst[e];
        atomicAdd(&h[d.x >> BSHIFT], 1);
        atomicAdd(&h[d.y >> BSHIFT], 1);
        atomicAdd(&h[d.z >> BSHIFT], 1);
        atomicAdd(&h[d.w >> BSHIFT], 1);
    }
    for (int e = vend + t; e < e1; e += 256)
        atomicAdd(&h[dst[e] >> BSHIFT], 1);
    __syncthreads();
    for (int i = t; i < nbin; i += 256)
        res[i] = h[i] ? atomicAdd(&binCur[i], h[i]) : 0;
    __syncthreads();
    for (int i = t; i < nbin; i += 256) h[i] = 0;
    __syncthreads();
    for (int e = e0 + t * 4; e < vend; e += 1024) {
        int4 d = *(const int4*)&dst[e];
        int4 s = *(const int4*)&src[e];
        int b0 = d.x >> BSHIFT;
        int p0 = res[b0] + atomicAdd(&h[b0], 1);
        tmp[p0] = ((unsigned)s.x << BSHIFT) | (unsigned)(d.x & (BINW - 1));
        int b1 = d.y >> BSHIFT;
        int p1 = res[b1] + atomicAdd(&h[b1], 1);
        tmp[p1] = ((unsigned)s.y << BSHIFT) | (unsigned)(d.y & (BINW - 1));
        int b2 = d.z >> BSHIFT;
        int p2 = res[b2] + atomicAdd(&h[b2], 1);
        tmp[p2] = ((unsigned)s.z << BSHIFT) | (unsigned)(d.z & (BINW - 1));
        int b3 = d.w >> BSHIFT;
        int p3 = res[b3] + atomicAdd(&h[b3], 1);
        tmp[p3] = ((unsigned)s.w << BSHIFT) | (unsigned)(d.w & (BINW - 1));
    }
    for (int e = vend + t; e < e1; e += 256) {
        int d = dst[e];
        int b = d >> BSHIFT;
        int p = res[b] + atomicAdd(&h[b], 1);
        tmp[p] = ((unsigned)src[e] << BSHIFT) | (unsigned)(d & (BINW - 1));
    }
}

__global__ __launch_bounds__(256) void k_csr(const unsigned* __restrict__ tmp,
                                             const int* __restrict__ binBase,
                                             int n, int nbin,
                                             float* __restrict__ dinv,
                                             int* __restrict__ offs,
                                             int* __restrict__ csr) {
    __shared__ int ldeg[BINW];
    __shared__ int loff[BINW];
    __shared__ int pair[256];
    int b = blockIdx.x;
    int t = threadIdx.x;
    ldeg[t] = 0; ldeg[t + 256] = 0;
    __syncthreads();
    int lo = binBase[b], hi = binBase[b + 1];
    for (int p = lo + t; p < hi; p += 256)
        atomicAdd(&ldeg[tmp[p] & (BINW - 1u)], 1);
    __syncthreads();
    int a0 = ldeg[2 * t], a1 = ldeg[2 * t + 1];
    pair[t] = a0 + a1;
    __syncthreads();
    int v = pair[t];
    for (int d = 1; d < 256; d <<= 1) {
        int u = (t >= d) ? pair[t - d] : 0;
        __syncthreads();
        pair[t] += u;
        __syncthreads();
    }
    int ex = pair[t] - v;
    loff[2 * t] = ex;
    loff[2 * t + 1] = ex + a0;
    __syncthreads();
    int v0 = b << BSHIFT;
    for (int i = t; i < BINW; i += 256) {
        int vv = v0 + i;
        if (vv < n) {
            offs[vv] = lo + loff[i];
            dinv[vv] = 1.0f / sqrtf((float)(ldeg[i] + 1));
        }
    }
    if (t == 0 && b == nbin - 1) offs[n] = hi;
    __syncthreads();
    ldeg[t] = 0; ldeg[t + 256] = 0;
    __syncthreads();
    for (int p = lo + t; p < hi; p += 256) {
        unsigned u = tmp[p];
        int d0 = (int)(u & (BINW - 1u));
        int pos = loff[d0] + atomicAdd(&ldeg[d0], 1);
        csr[lo + pos] = (int)(u >> BSHIFT);
    }
}

// ---------------- aggregation: group-owns-row, depth-pipelined ----------------
// LPR=W/4 lanes form a group owning one dst row; each lane owns a 16B column
// slice for the whole row (no cross-lane reduce). DEPTH-deep double-buffered
// gathers: batch k+1's loads issue before batch k is consumed.
// L1S: gather S[u]*dinv[u] (layer 1). out = act(dinv[v]*(sum+self) + bias).
template <int W, int DEPTH, bool RELU, bool BIAS, bool L1S>
__global__ __launch_bounds__(256) void k_aggp(const float* __restrict__ S,
                                              const float* __restrict__ dinv,
                                              const int* __restrict__ offs,
                                              const int* __restrict__ csr,
                                              const float* __restrict__ bg,
                                              float* __restrict__ Y, int n) {
    constexpr int LPR = W / 4;      // lanes per row-group
    constexpr int GPW = 64 / LPR;   // rows per wave
    int lane = threadIdx.x & 63;
    int wave = threadIdx.x >> 6;
    int grp = lane / LPR;
    int j = lane % LPR;
    int v = blockIdx.x * (4 * GPW) + wave * GPW + grp;
    if (v >= n) return;
    float dv = dinv[v];
    float4 acc0, acc1 = make_float4(0.f, 0.f, 0.f, 0.f);
    {   // self-loop term
        float4 sv = *(const float4*)&S[(size_t)v * W + j * 4];
        float sc = L1S ? dv : 1.0f;
        acc0 = make_float4(sv.x * sc, sv.y * sc, sv.z * sc, sv.w * sc);
    }
    int e0 = offs[v], re = offs[v + 1];
    int nb = (re - e0) / DEPTH;
    float4 bA[DEPTH], bB[DEPTH];
    float dA[DEPTH], dB[DEPTH];
    int iA[DEPTH], iB[DEPTH];
    auto loadIdx = [&](int* ix, int base) {
#pragma unroll
        for (int d = 0; d < DEPTH; ++d)
            ix[d] = __builtin_nontemporal_load(&csr[base + d]);
    };
    auto gather = [&](float4* bf, float* ds, const int* ix) {
#pragma unroll
        for (int d = 0; d < DEPTH; ++d) {
            bf[d] = *(const float4*)&S[(size_t)ix[d] * W + j * 4];
            if (L1S) ds[d] = dinv[ix[d]];
        }
    };
    auto consume = [&](const float4* bf, const float* ds) {
#pragma unroll
        for (int d = 0; d < DEPTH; ++d) {
            float sc = L1S ? ds[d] : 1.0f;
            if (d & 1) { acc1.x += bf[d].x * sc; acc1.y += bf[d].y * sc;
                         acc1.z += bf[d].z * sc; acc1.w += bf[d].w * sc; }
            else       { acc0.x += bf[d].x * sc; acc0.y += bf[d].y * sc;
                         acc0.z += bf[d].z * sc; acc0.w += bf[d].w * sc; }
        }
    };
    if (nb >= 1) {
        loadIdx(iA, e0);
        gather(bA, dA, iA);
        if (nb >= 2) loadIdx(iB, e0 + DEPTH);
        int b = 0;
        while (b + 2 <= nb) {
            gather(bB, dB, iB);                        // batch b+1 in flight
            if (b + 2 < nb) loadIdx(iA, e0 + (b + 2) * DEPTH);
            consume(bA, dA);                           // waits only on batch b
            if (b + 2 < nb) {
                gather(bA, dA, iA);                    // batch b+2 in flight
                if (b + 3 < nb) loadIdx(iB, e0 + (b + 3) * DEPTH);
            }
            consume(bB, dB);
            b += 2;
        }
        if (b < nb) consume(bA, dA);
    }
    for (int k = e0 + nb * DEPTH; k < re; ++k) {       // tail edges
        int u = __builtin_nontemporal_load(&csr[k]);
        float4 a = *(const float4*)&S[(size_t)u * W + j * 4];
        float sc = L1S ? dinv[u] : 1.0f;
        acc0.x += a.x * sc; acc0.y += a.y * sc; acc0.z += a.z * sc; acc0.w += a.w * sc;
    }
    acc0.x += acc1.x; acc0.y += acc1.y; acc0.z += acc1.z; acc0.w += acc1.w;
    float4 r;
    r.x = dv * acc0.x; r.y = dv * acc0.y; r.z = dv * acc0.z; r.w = dv * acc0.w;
    if (BIAS) {
        float4 bv = *(const float4*)&bg[j * 4];
        r.x += bv.x; r.y += bv.y; r.z += bv.z; r.w += bv.w;
    }
    if (RELU) {
        r.x = fmaxf(r.x, 0.f); r.y = fmaxf(r.y, 0.f);
        r.z = fmaxf(r.z, 0.f); r.w = fmaxf(r.w, 0.f);
    }
    *(float4*)&Y[(size_t)v * W + j * 4] = r;
}

// W=16 agg + gemm5 fused, group-owns-row (4-lane groups, 16 rows/wave):
// h4 = relu(dinv*sum + b4); Y[v] = (h4 . W5) * dinv[v]
template <int DEPTH>
__global__ __launch_bounds__(256) void k_agg16g5(const float* __restrict__ S,
                                                 const float* __restrict__ dinv,
                                                 const int* __restrict__ offs,
                                                 const int* __restrict__ csr,
                                                 const float* __restrict__ b4,
                                                 const float* __restrict__ W5,
                                                 float* __restrict__ Y, int n) {
    constexpr int W = 16, LPR = 4, GPW = 16;
    int lane = threadIdx.x & 63;
    int wave = threadIdx.x >> 6;
    int grp = lane / LPR;
    int j = lane % LPR;
    int v = blockIdx.x * (4 * GPW) + wave * GPW + grp;
    if (v >= n) return;
    float dv = dinv[v];
    float4 acc0 = *(const float4*)&S[(size_t)v * W + j * 4];  // self (pre-scaled)
    float4 acc1 = make_float4(0.f, 0.f, 0.f, 0.f);
    int e0 = offs[v], re = offs[v + 1];
    int nb = (re - e0) / DEPTH;
    float4 bA[DEPTH], bB[DEPTH];
    int iA[DEPTH], iB[DEPTH];
    auto loadIdx = [&](int* ix, int base) {
#pragma unroll
        for (int d = 0; d < DEPTH; ++d)
            ix[d] = __builtin_nontemporal_load(&csr[base + d]);
    };
    auto gather = [&](float4* bf, const int* ix) {
#pragma unroll
        for (int d = 0; d < DEPTH; ++d)
            bf[d] = *(const float4*)&S[(size_t)ix[d] * W + j * 4];
    };
    auto consume = [&](const float4* bf) {
#pragma unroll
        for (int d = 0; d < DEPTH; ++d) {
            if (d & 1) { acc1.x += bf[d].x; acc1.y += bf[d].y;
                         acc1.z += bf[d].z; acc1.w += bf[d].w; }
            else       { acc0.x += bf[d].x; acc0.y += bf[d].y;
                         acc0.z += bf[d].z; acc0.w += bf[d].w; }
        }
    };
    if (nb >= 1) {
        loadIdx(iA, e0);
        gather(bA, iA);
        if (nb >= 2) loadIdx(iB, e0 + DEPTH);
        int b = 0;
        while (b + 2 <= nb) {
            gather(bB, iB);
            if (b + 2 < nb) loadIdx(iA, e0 + (b + 2) * DEPTH);
            consume(bA);
            if (b + 2 < nb) {
                gather(bA, iA);
                if (b + 3 < nb) loadIdx(iB, e0 + (b + 3) * DEPTH);
            }
            consume(bB);
            b += 2;
        }
        if (b < nb) consume(bA);
    }
    for (int k = e0 + nb * DEPTH; k < re; ++k) {
        int u = __builtin_nontemporal_load(&csr[k]);
        float4 a = *(const float4*)&S[(size_t)u * W + j * 4];
        acc0.x += a.x; acc0.y += a.y; acc0.z += a.z; acc0.w += a.w;
    }
    acc0.x += acc1.x; acc0.y += acc1.y; acc0.z += acc1.z; acc0.w += acc1.w;
    float4 bv = *(const float4*)&b4[j * 4];
    float4 w5 = *(const float4*)&W5[j * 4];
    float hx = fmaxf(dv * acc0.x + bv.x, 0.f);
    float hy = fmaxf(dv * acc0.y + bv.y, 0.f);
    float hz = fmaxf(dv * acc0.z + bv.z, 0.f);
    float hw = fmaxf(dv * acc0.w + bv.w, 0.f);
    float p = hx * w5.x + hy * w5.y + hz * w5.z + hw * w5.w;
    p += __shfl_xor(p, 1);   // 4-lane groups are xor-1/2 closed
    p += __shfl_xor(p, 2);
    if (j == 0) Y[v] = p * dv;
}

__global__ __launch_bounds__(256) void k_agg1(const float* __restrict__ S,
                                              const float* __restrict__ dinv,
                                              const int* __restrict__ offs,
                                              const int* __restrict__ csr,
                                              const float* __restrict__ bg,
                                              float* __restrict__ Y, int n) {
    int v = blockIdx.x * 256 + threadIdx.x;
    if (v >= n) return;
    float s0 = S[v], s1 = 0.f, s2 = 0.f, s3 = 0.f;
    int e = offs[v], re = offs[v + 1];
    for (; e + 4 <= re; e += 4) {
        int i0 = csr[e], i1 = csr[e + 1], i2 = csr[e + 2], i3 = csr[e + 3];
        s0 += S[i0]; s1 += S[i1]; s2 += S[i2]; s3 += S[i3];
    }
    for (; e < re; ++e) s0 += S[csr[e]];
    Y[v] = dinv[v] * ((s0 + s1) + (s2 + s3)) + bg[0];
}

// ---------------- tall-skinny GEMMs ----------------
template <int IN, int OUT, int EPI, int NR>
__global__ __launch_bounds__(256) void k_gemm(const float* __restrict__ X,
                                              const float* __restrict__ Wg,
                                              const float* __restrict__ bg,
                                              const float* __restrict__ dinv,
                                              float* __restrict__ Y, int nrows) {
    constexpr int TPR = OUT / 4;
    constexpr int GROUPS = 256 / TPR;
    constexpr int ROWS = GROUPS * NR;
    __shared__ __align__(16) float Wl[IN * OUT];
    __shared__ __align__(16) float xl[ROWS * IN];
    __shared__ float bl[OUT];
    int tid = threadIdx.x;
    for (int i = tid; i < IN * OUT; i += 256) Wl[i] = Wg[i];
    if (EPI == 0)
        for (int i = tid; i < OUT; i += 256) bl[i] = bg[i];
    int base = blockIdx.x * ROWS;
    for (int i = tid; i < ROWS * IN; i += 256) {
        int r = base + i / IN;
        xl[i] = (r < nrows) ? X[(size_t)base * IN + i] : 0.0f;
    }
    __syncthreads();
    int g = tid / TPR;
    int c0 = (tid % TPR) * 4;
    float4 acc[NR];
#pragma unroll
    for (int r = 0; r < NR; ++r) acc[r] = make_float4(0.f, 0.f, 0.f, 0.f);
#pragma unroll 8
    for (int k = 0; k < IN; ++k) {
        float4 w = *(const float4*)&Wl[k * OUT + c0];
#pragma unroll
        for (int r = 0; r < NR; ++r) {
            float a = xl[(g * NR + r) * IN + k];
            acc[r].x += a * w.x; acc[r].y += a * w.y;
            acc[r].z += a * w.z; acc[r].w += a * w.w;
        }
    }
#pragma unroll
    for (int r = 0; r < NR; ++r) {
        int row = base + g * NR + r;
        if (row >= nrows) continue;
        float4 o = acc[r];
        if (EPI == 0) {
            o.x = fmaxf(o.x + bl[c0], 0.f);
            o.y = fmaxf(o.y + bl[c0 + 1], 0.f);
            o.z = fmaxf(o.z + bl[c0 + 2], 0.f);
            o.w = fmaxf(o.w + bl[c0 + 3], 0.f);
        } else {
            float d0 = dinv[row];
            o.x *= d0; o.y *= d0; o.z *= d0; o.w *= d0;
        }
        *(float4*)&Y[(size_t)row * OUT + c0] = o;
    }
}

extern "C" void kernel_launch(void* const* d_in, const int* in_sizes, int n_in,
                              void* d_out, int out_size, void* d_ws, size_t ws_size,
                              hipStream_t stream) {
    const float* x  = (const float*)d_in[0];
    const int*   ei = (const int*)d_in[1];
    const float* W1 = (const float*)d_in[2];  const float* b1 = (const float*)d_in[3];
    const float* W2 = (const float*)d_in[4];  const float* b2 = (const float*)d_in[5];
    const float* W3 = (const float*)d_in[6];  const float* b3 = (const float*)d_in[7];
    const float* W4 = (const float*)d_in[8];  const float* b4 = (const float*)d_in[9];
    const float* W5 = (const float*)d_in[10]; const float* b5 = (const float*)d_in[11];

    const int N = in_sizes[0] / 64;   // 100000
    const int E = in_sizes[1] / 2;    // 1600000
    const int* src = ei;
    const int* dst = ei + E;
    const int nbin = (N + BINW - 1) / BINW;   // 196

    char* ws = (char*)d_ws;
    size_t off = 0;
    auto alloc = [&](size_t bytes) -> void* {
        void* p = ws + off;
        off = (off + bytes + 255) & ~(size_t)255;
        return p;
    };
    float* dinv    = (float*)alloc((size_t)N * 4);
    int*   offs    = (int*)alloc((size_t)(N + 1) * 4);
    int*   binCnt  = (int*)alloc((size_t)NBIN_MAX * 4);
    int*   binBase = (int*)alloc((size_t)(NBIN_MAX + 1) * 4);
    int*   binCur  = (int*)alloc((size_t)NBIN_MAX * 4);
    int*   csr     = (int*)alloc((size_t)E * 4);
    float* s5      = (float*)alloc((size_t)N * 4);
    float* A       = (float*)alloc((size_t)N * 128 * 4);  // h1 -> h3
    float* B       = (float*)alloc((size_t)N * 64 * 4);   // agg1/s2/s3/s4
    float* C       = (float*)alloc((size_t)N * 64 * 4);   // tmp -> h2
    unsigned* tmp  = (unsigned*)C;

    hipMemsetAsync(binCnt, 0, (size_t)NBIN_MAX * 4, stream);

    k_hist<<<256, 256, 0, stream>>>(dst, E, nbin, binCnt);
    k_binscan<<<1, 256, 0, stream>>>(binCnt, nbin, binBase, binCur);
    k_binfill<<<(E + CHUNK - 1) / CHUNK, 256, 0, stream>>>(src, dst, E, nbin, binCur, tmp);
    k_csr<<<nbin, 256, 0, stream>>>(tmp, binBase, N, nbin, dinv, offs, csr);

    // Layer 1: agg1 = A.x (gathers x, per-edge dinv); h1 = relu(agg1@W1+b1)
    k_aggp<64, 3, false, false, true><<<(N + 15) / 16, 256, 0, stream>>>(x, dinv, offs, csr, nullptr, B, N);
    k_gemm<64, 128, 0, 4><<<(N + 31) / 32, 256, 0, stream>>>(B, W1, b1, nullptr, A, N);
    // Layer 2
    k_gemm<128, 64, 1, 2><<<(N + 31) / 32, 256, 0, stream>>>(A, W2, nullptr, dinv, B, N);
    k_aggp<64, 4, true, true, false><<<(N + 15) / 16, 256, 0, stream>>>(B, dinv, offs, csr, b2, C, N);
    // Layer 3
    k_gemm<64, 32, 1, 2><<<(N + 63) / 64, 256, 0, stream>>>(C, W3, nullptr, dinv, B, N);
    k_aggp<32, 4, true, true, false><<<(N + 31) / 32, 256, 0, stream>>>(B, dinv, offs, csr, b3, A, N);
    // Layer 4: s4 = (h3@W4)*dinv, fused agg+gemm5 -> s5 (h4 never stored)
    k_gemm<32, 16, 1, 2><<<(N + 127) / 128, 256, 0, stream>>>(A, W4, nullptr, dinv, B, N);
    k_agg16g5<4><<<(N + 63) / 64, 256, 0, stream>>>(B, dinv, offs, csr, b4, W5, s5, N);
    // Layer 5: out = A.s5 + b5
    k_agg1<<<(N + 255) / 256, 256, 0, stream>>>(s5, dinv, offs, csr, b5, (float*)d_out, N);
}